// Round 9
// baseline (436.756 us; speedup 1.0000x reference)
//
#include <hip/hip_runtime.h>
#include <hip/hip_fp16.h>

// ---------------------------------------------------------------------------
// GraphSAGE (3x SAGEConv mean-agg + BN/ReLU) + link decoder.
// R9 changes vs R8:
//  - scatter replaced by 2-pass binned build: binA appends (src,dst) pairs to
//    per-(blockgroup&7, dst>>7) cells (group ~ XCD -> single-owner lines);
//    binB: one block per 128-node bucket, LDS per-node cursors, localized
//    full-line writes into edges[]. Fixes the 16x write amplification
//    (WRITE_SIZE 55.5MB for 3.2MB logical).
//  - mm / agg / decode unchanged from R8.
// ---------------------------------------------------------------------------

typedef unsigned int uint;
using s16x8 = __attribute__((ext_vector_type(8))) short;
using f32x4 = __attribute__((ext_vector_type(4))) float;

#define BIN_CAP 768   // expected 256/cell (32 sigma headroom)

__device__ inline void bsplit(float v, ushort& hi, ushort& lo) {
    // round-to-nearest-even bf16 split: v ~= hi + lo to ~2^-17 rel
    uint u = __float_as_uint(v);
    uint hb = (u + 0x7FFFu + ((u >> 16) & 1u)) >> 16;
    hi = (ushort)hb;
    float r = v - __uint_as_float(hb << 16);
    uint u2 = __float_as_uint(r);
    lo = (ushort)((u2 + 0x7FFFu + ((u2 >> 16) & 1u)) >> 16);
}

__device__ inline ushort f2h(float v) { return __half_as_ushort(__float2half(v)); }

__device__ inline float4 h4f(uint2 r) {
    float2 fa = __half22float2(*(const __half2*)&r.x);
    float2 fb = __half22float2(*(const __half2*)&r.y);
    return make_float4(fa.x, fa.y, fb.x, fb.y);
}

// swizzle a ushort index within its 64-ushort K-slice: chunk ^= (row&7)
__device__ inline uint swz(uint i, uint r) {
    return (i & ~63u) | ((i ^ (r << 3)) & 56u) | (i & 7u);
}

// async global->LDS, 16 bytes per lane
__device__ inline void gload16(const void* g, void* l) {
    __builtin_amdgcn_global_load_lds(
        (const __attribute__((address_space(1))) unsigned int*)g,
        (__attribute__((address_space(3))) unsigned int*)l, 16, 0, 0);
}

// ---------------- CSR build ----------------
__global__ void count_kernel(const int* __restrict__ dst, int* __restrict__ cnt, int E) {
    int i = blockIdx.x * blockDim.x + threadIdx.x;
    if (i < E) atomicAdd(&cnt[dst[i]], 1);
}

__global__ void scanA_kernel(const int* __restrict__ cnt, int* __restrict__ ptr,
                             int* __restrict__ tilesum, int n) {
    __shared__ int sd[1024];
    int t = threadIdx.x;
    int i = blockIdx.x * 1024 + t;
    int v = (i < n) ? cnt[i] : 0;
    sd[t] = v;
    __syncthreads();
    #pragma unroll
    for (int off = 1; off < 1024; off <<= 1) {
        int add = (t >= off) ? sd[t - off] : 0;
        __syncthreads();
        sd[t] += add;
        __syncthreads();
    }
    if (i < n) ptr[i] = sd[t] - v;              // local exclusive
    if (t == 1023) tilesum[blockIdx.x] = sd[t]; // tile total
}

__global__ void scanB_kernel(int* __restrict__ tilesum, int* __restrict__ ptr,
                             int ntiles, int n) {
    if (threadIdx.x == 0 && blockIdx.x == 0) {
        int running = 0;
        for (int b = 0; b < ntiles; ++b) {
            int t = tilesum[b];
            tilesum[b] = running;
            running += t;
        }
        ptr[n] = running;
    }
}

__global__ void scanC_kernel(int* __restrict__ ptr, const int* __restrict__ tilesum, int n) {
    int i = blockIdx.x * blockDim.x + threadIdx.x;
    if (i < n) ptr[i] += tilesum[i >> 10];
}

// pass A: bin (src,dst) into cells by (blockgroup&7, dst>>7)
__global__ __launch_bounds__(256) void binA_kernel(
    const int* __restrict__ src, const int* __restrict__ dst,
    int* __restrict__ ccnt, uint2* __restrict__ binbuf, int nb, int E) {
    const int g = blockIdx.x & 7;
    for (int i = blockIdx.x * 256 + threadIdx.x; i < E; i += gridDim.x * 256) {
        int d = dst[i];
        int cell = g * nb + (d >> 7);
        int c = atomicAdd(&ccnt[cell], 1);
        if (c < BIN_CAP) binbuf[(size_t)cell * BIN_CAP + c] = make_uint2((uint)src[i], (uint)d);
    }
}

// pass B: one block per bucket (128 nodes); LDS per-node cursors; localized writes
__global__ __launch_bounds__(256) void binB_kernel(
    const int* __restrict__ ccnt, const uint2* __restrict__ binbuf,
    const int* __restrict__ ptr, int* __restrict__ edges, int nb) {
    __shared__ int lcnt[128];
    const int b = blockIdx.x;
    if (threadIdx.x < 128) lcnt[threadIdx.x] = 0;
    __syncthreads();
    for (int g = 0; g < 8; ++g) {
        int cell = g * nb + b;
        int cn = ccnt[cell];
        cn = cn < BIN_CAP ? cn : BIN_CAP;
        const uint2* cb = binbuf + (size_t)cell * BIN_CAP;
        for (int i = threadIdx.x; i < cn; i += 256) {
            uint2 p = cb[i];
            int off = atomicAdd(&lcnt[p.y & 127], 1);
            edges[ptr[p.y] + off] = (int)p.x;
        }
    }
}

// ---------------- conversions (pre-swizzled stores) ----------------
// A row (K=256): [hi(0..255) | lo(0..255)] (KP=512), chunk-swizzled per slice
__global__ __launch_bounds__(256) void convx_kernel(const float* __restrict__ x,
                                                    ushort* __restrict__ A3, int total) {
    int e = blockIdx.x * 256 + threadIdx.x;   // total = N*64 (float4 groups)
    if (e >= total) return;
    uint row = e >> 6;
    uint k4 = (e & 63) << 2;
    float4 v = *(const float4*)(x + (size_t)row * 256 + k4);
    ushort4 hi, lo;
    bsplit(v.x, hi.x, lo.x); bsplit(v.y, hi.y, lo.y);
    bsplit(v.z, hi.z, lo.z); bsplit(v.w, hi.w, lo.w);
    ushort* d = A3 + (size_t)row * 512;
    *(ushort4*)(d + swz(k4, row))       = hi;
    *(ushort4*)(d + swz(k4 + 256, row)) = lo;
}

// WS[n][k'] n-major, k' = [Wh | Wlo | Wh], chunk-swizzled per slice
__global__ void wprep_all_kernel(
    const float* __restrict__ w1l, const float* __restrict__ w1r,
    const float* __restrict__ w2l, const float* __restrict__ w2r,
    const float* __restrict__ w3l, const float* __restrict__ w3r,
    const float* __restrict__ dw1,
    ushort* __restrict__ WS1, ushort* __restrict__ WS2,
    ushort* __restrict__ WS3, ushort* __restrict__ WS4)
{
    int which = blockIdx.y;
    uint n = blockIdx.x;
    uint k = threadIdx.x;
    const float *wa, *wb;
    uint K, lda, aoff, boff;
    ushort* WS;
    switch (which) {
        case 0:  wa = w1l; wb = w1r; K = 256; lda = 256; aoff = 0; boff = 0;   WS = WS1; break;
        case 1:  wa = w2l; wb = w2r; K = 128; lda = 128; aoff = 0; boff = 0;   WS = WS2; break;
        case 2:  wa = w3l; wb = w3r; K = 128; lda = 128; aoff = 0; boff = 0;   WS = WS3; break;
        default: wa = dw1; wb = dw1; K = 128; lda = 256; aoff = 0; boff = 128; WS = WS4; break;
    }
    if (k >= K) return;
    const float* srcr = (n < 128) ? (wa + (size_t)n * lda + aoff)
                                  : (wb + (size_t)(n - 128) * lda + boff);
    ushort hi, lo;
    bsplit(srcr[k], hi, lo);
    ushort* d = WS + (size_t)n * 3 * K;
    d[swz(k, n)]         = hi;
    d[swz(K + k, n)]     = lo;
    d[swz(2 * K + k, n)] = hi;
}

// ---------------- MFMA GEMM ----------------
// Block = 128 rows x 256 cols. 4 waves, each 64x128.
// A[M][KP] = [hi|lo] pre-swizzled; W[256][KP*3/2] = [Wh|Wlo|Wh] pre-swizzled.
// Staging = global_load_lds 16B into LINEAR LDS; ds_read applies the XOR.
// Cl (cols 0..127) written fp16; Cr written fp16 iff CRF16 else f32.
template <int KP, int CRF16>
__global__ __launch_bounds__(256, 2) void mm_kernel(const ushort* __restrict__ A,
                                                    const ushort* __restrict__ WS,
                                                    ushort* __restrict__ Cl,
                                                    void* __restrict__ Cr_, int M) {
    constexpr int KS  = (KP / 64) + (KP / 128);   // 12 (KP=512) or 6 (KP=256)
    constexpr int WKP = KP + KP / 2;
    __shared__ ushort At[128 * 64];
    __shared__ ushort Bt[256 * 64];
    const int t = threadIdx.x;
    const int lane = t & 63;
    const int wave = t >> 6;
    const int wm = wave >> 1, wn = wave & 1;      // 2 row-halves x 2 col-halves
    const int row0 = blockIdx.x * 128;
    const int l15 = lane & 15;
    const int l4 = lane >> 4;
    const int l8 = lane >> 3;                     // staging row within 8-row group
    const int c8 = lane & 7;                      // staging chunk within row

    f32x4 acc[4][8] = {};

    for (int s = 0; s < KS; ++s) {
        const int as = (s < KP / 128) ? s : s - (KP / 128);
        #pragma unroll
        for (int j = 0; j < 4; ++j) {
            int jj = wave + j * 4;                // A group 0..15
            int r = jj * 8 + l8;
            gload16(A + (size_t)(row0 + r) * KP + as * 64 + c8 * 8,
                    (char*)At + jj * 1024 + lane * 16);
        }
        #pragma unroll
        for (int j = 0; j < 8; ++j) {
            int jj = wave + j * 4;                // B group 0..31
            int r = jj * 8 + l8;
            gload16(WS + (size_t)r * WKP + s * 64 + c8 * 8,
                    (char*)Bt + jj * 1024 + lane * 16);
        }
        __syncthreads();
        #pragma unroll
        for (int kk = 0; kk < 64; kk += 32) {
            s16x8 af[4], bf[8];
            #pragma unroll
            for (int mi = 0; mi < 4; ++mi) {
                int r = wm * 64 + mi * 16 + l15;
                int off = (kk + l4 * 8) ^ ((r & 7) * 8);
                af[mi] = *(const s16x8*)&At[r * 64 + off];
            }
            #pragma unroll
            for (int ni = 0; ni < 8; ++ni) {
                int r = wn * 128 + ni * 16 + l15;
                int off = (kk + l4 * 8) ^ ((r & 7) * 8);
                bf[ni] = *(const s16x8*)&Bt[r * 64 + off];
            }
            #pragma unroll
            for (int mi = 0; mi < 4; ++mi)
                #pragma unroll
                for (int ni = 0; ni < 8; ++ni)
                    acc[mi][ni] = __builtin_amdgcn_mfma_f32_16x16x32_bf16(
                        af[mi], bf[ni], acc[mi][ni], 0, 0, 0);
        }
        __syncthreads();
    }
    // ---- epilogue: row = (lane>>4)*4+j, col = lane&15 within 16x16
    #pragma unroll
    for (int mi = 0; mi < 4; ++mi) {
        int rbase = row0 + wm * 64 + mi * 16 + l4 * 4;
        #pragma unroll
        for (int ni = 0; ni < 8; ++ni) {
            int col = ni * 16 + l15;
            #pragma unroll
            for (int j = 0; j < 4; ++j) {
                int r = rbase + j;
                if (r < M) {
                    if (wn == 0) {
                        Cl[(size_t)r * 128 + col] = f2h(acc[mi][ni][j]);
                    } else if (CRF16) {
                        ((ushort*)Cr_)[(size_t)r * 128 + col] = f2h(acc[mi][ni][j]);
                    } else {
                        ((float*)Cr_)[(size_t)r * 128 + col] = acc[mi][ni][j];
                    }
                }
            }
        }
    }
}

// ---------------- aggregation ----------------
// One node per wave; lanes 0-31 even edge slots, 32-63 odd; shfl_xor combine.
// tl is fp16 (256B/row gathers); root tr is f32 (streamed).
// out = opt_bn_relu( mean tl[src] + bl + tr[i] ), emits h[n][256]=[hi|lo] swz.
__global__ __launch_bounds__(256, 4) void agg_kernel(
    const ushort* __restrict__ tl, const float* __restrict__ tr,
    const int* __restrict__ ptr, const int* __restrict__ edges,
    const float* __restrict__ bl,
    const float* __restrict__ bng, const float* __restrict__ bnb,
    const float* __restrict__ bnm, const float* __restrict__ bnv,
    int do_bn, ushort* __restrict__ h3, int n) {
    const int wave = threadIdx.x >> 6;
    const int lane = threadIdx.x & 63;
    const uint node = blockIdx.x * 4 + wave;
    if (node >= (uint)n) return;
    const int half = lane >> 5;
    const uint q4 = (lane & 31) << 2;             // 4 feats per lane
    const int p0 = ptr[node], p1 = ptr[node + 1];
    float4 a0 = make_float4(0.f, 0.f, 0.f, 0.f), a1 = a0, a2 = a0, a3 = a0;
    float4 a4 = a0, a5 = a0, a6 = a0, a7 = a0;
    int e = p0 + half;
    for (; e + 14 < p1; e += 16) {                // 8 edges per half per iter
        int i0 = edges[e],      i1 = edges[e + 2],  i2 = edges[e + 4],  i3 = edges[e + 6];
        int i4 = edges[e + 8],  i5 = edges[e + 10], i6 = edges[e + 12], i7 = edges[e + 14];
        uint2 r0 = *(const uint2*)(tl + (size_t)i0 * 128 + q4);
        uint2 r1 = *(const uint2*)(tl + (size_t)i1 * 128 + q4);
        uint2 r2 = *(const uint2*)(tl + (size_t)i2 * 128 + q4);
        uint2 r3 = *(const uint2*)(tl + (size_t)i3 * 128 + q4);
        uint2 r4 = *(const uint2*)(tl + (size_t)i4 * 128 + q4);
        uint2 r5 = *(const uint2*)(tl + (size_t)i5 * 128 + q4);
        uint2 r6 = *(const uint2*)(tl + (size_t)i6 * 128 + q4);
        uint2 r7 = *(const uint2*)(tl + (size_t)i7 * 128 + q4);
        float4 v0 = h4f(r0), v1 = h4f(r1), v2 = h4f(r2), v3 = h4f(r3);
        float4 v4 = h4f(r4), v5 = h4f(r5), v6 = h4f(r6), v7 = h4f(r7);
        a0.x += v0.x; a0.y += v0.y; a0.z += v0.z; a0.w += v0.w;
        a1.x += v1.x; a1.y += v1.y; a1.z += v1.z; a1.w += v1.w;
        a2.x += v2.x; a2.y += v2.y; a2.z += v2.z; a2.w += v2.w;
        a3.x += v3.x; a3.y += v3.y; a3.z += v3.z; a3.w += v3.w;
        a4.x += v4.x; a4.y += v4.y; a4.z += v4.z; a4.w += v4.w;
        a5.x += v5.x; a5.y += v5.y; a5.z += v5.z; a5.w += v5.w;
        a6.x += v6.x; a6.y += v6.y; a6.z += v6.z; a6.w += v6.w;
        a7.x += v7.x; a7.y += v7.y; a7.z += v7.z; a7.w += v7.w;
    }
    for (; e < p1; e += 2) {
        int i0 = edges[e];
        float4 v0 = h4f(*(const uint2*)(tl + (size_t)i0 * 128 + q4));
        a0.x += v0.x; a0.y += v0.y; a0.z += v0.z; a0.w += v0.w;
    }
    float4 s;
    s.x = ((a0.x + a1.x) + (a2.x + a3.x)) + ((a4.x + a5.x) + (a6.x + a7.x));
    s.y = ((a0.y + a1.y) + (a2.y + a3.y)) + ((a4.y + a5.y) + (a6.y + a7.y));
    s.z = ((a0.z + a1.z) + (a2.z + a3.z)) + ((a4.z + a5.z) + (a6.z + a7.z));
    s.w = ((a0.w + a1.w) + (a2.w + a3.w)) + ((a4.w + a5.w) + (a6.w + a7.w));
    // combine even/odd halves (lane <-> lane^32)
    s.x += __shfl_xor(s.x, 32);
    s.y += __shfl_xor(s.y, 32);
    s.z += __shfl_xor(s.z, 32);
    s.w += __shfl_xor(s.w, 32);
    if (half == 0) {
        float inv = 1.f / fmaxf((float)(p1 - p0), 1.f);
        float4 r = *(const float4*)(tr + (size_t)node * 128 + q4);
        float4 b = *(const float4*)(bl + q4);
        float4 val;
        val.x = fmaf(s.x, inv, b.x) + r.x;
        val.y = fmaf(s.y, inv, b.y) + r.y;
        val.z = fmaf(s.z, inv, b.z) + r.z;
        val.w = fmaf(s.w, inv, b.w) + r.w;
        if (do_bn) {
            float4 g = *(const float4*)(bng + q4);
            float4 be = *(const float4*)(bnb + q4);
            float4 m = *(const float4*)(bnm + q4);
            float4 vv = *(const float4*)(bnv + q4);
            val.x = fmaxf(fmaf(val.x - m.x, g.x * rsqrtf(vv.x + 1e-5f), be.x), 0.f);
            val.y = fmaxf(fmaf(val.y - m.y, g.y * rsqrtf(vv.y + 1e-5f), be.y), 0.f);
            val.z = fmaxf(fmaf(val.z - m.z, g.z * rsqrtf(vv.z + 1e-5f), be.z), 0.f);
            val.w = fmaxf(fmaf(val.w - m.w, g.w * rsqrtf(vv.w + 1e-5f), be.w), 0.f);
        }
        ushort4 hi, lo;
        bsplit(val.x, hi.x, lo.x); bsplit(val.y, hi.y, lo.y);
        bsplit(val.z, hi.z, lo.z); bsplit(val.w, hi.w, lo.w);
        ushort* d = h3 + (size_t)node * 256;
        *(ushort4*)(d + swz(q4, node))       = hi;
        *(ushort4*)(d + swz(q4 + 128, node)) = lo;
    }
}

// ---------------- decoder: relu(u[s] + v[d] + b) . w2 + b2 (u,v fp16) -------
__global__ __launch_bounds__(256) void decode_kernel(
    const ushort* __restrict__ u, const ushort* __restrict__ v,
    const int* __restrict__ eli, const float* __restrict__ db1,
    const float* __restrict__ dw2, const float* __restrict__ db2,
    float* __restrict__ out, int L) {
    __shared__ float sb[128], sw[128];
    if (threadIdx.x < 128) {
        sb[threadIdx.x] = db1[threadIdx.x];
        sw[threadIdx.x] = dw2[threadIdx.x];
    }
    __syncthreads();
    int p = blockIdx.x * 256 + threadIdx.x;
    if (p >= L) return;
    int s = eli[p], d = eli[L + p];
    const ushort* up = u + (size_t)s * 128;
    const ushort* vp = v + (size_t)d * 128;
    float acc = db2[0];
    #pragma unroll 8
    for (int o = 0; o < 128; o += 4) {
        float4 a = h4f(*(const uint2*)(up + o));
        float4 b = h4f(*(const uint2*)(vp + o));
        float4 bb = *(const float4*)(&sb[o]);
        float4 w = *(const float4*)(&sw[o]);
        acc += fmaxf(a.x + b.x + bb.x, 0.f) * w.x;
        acc += fmaxf(a.y + b.y + bb.y, 0.f) * w.y;
        acc += fmaxf(a.z + b.z + bb.z, 0.f) * w.z;
        acc += fmaxf(a.w + b.w + bb.w, 0.f) * w.w;
    }
    out[p] = acc;
}

extern "C" void kernel_launch(void* const* d_in, const int* in_sizes, int n_in,
                              void* d_out, int out_size, void* d_ws, size_t ws_size,
                              hipStream_t stream) {
    const float* x    = (const float*)d_in[0];
    const int*   ei   = (const int*)d_in[1];
    const int*   eli  = (const int*)d_in[2];
    const float* w1l  = (const float*)d_in[3];
    const float* b1l  = (const float*)d_in[4];
    const float* w1r  = (const float*)d_in[5];
    const float* w2l  = (const float*)d_in[6];
    const float* b2l  = (const float*)d_in[7];
    const float* w2r  = (const float*)d_in[8];
    const float* w3l  = (const float*)d_in[9];
    const float* b3l  = (const float*)d_in[10];
    const float* w3r  = (const float*)d_in[11];
    const float* bn1g = (const float*)d_in[12];
    const float* bn1b = (const float*)d_in[13];
    const float* bn1m = (const float*)d_in[14];
    const float* bn1v = (const float*)d_in[15];
    const float* bn2g = (const float*)d_in[16];
    const float* bn2b = (const float*)d_in[17];
    const float* bn2m = (const float*)d_in[18];
    const float* bn2v = (const float*)d_in[19];
    const float* dw1  = (const float*)d_in[20];
    const float* db1  = (const float*)d_in[21];
    const float* dw2  = (const float*)d_in[22];
    const float* db2  = (const float*)d_in[23];
    float* out = (float*)d_out;

    const int N = in_sizes[0] / 256;
    const int E = in_sizes[1] / 2;
    const int L = in_sizes[2] / 2;
    const int* src = ei;
    const int* dst = ei + E;
    const int ntiles = (N + 1023) >> 10;
    const int nblk = (N + 127) / 128;
    const int Npad = nblk * 128;
    const int nb = (N + 127) >> 7;                // 128-node buckets

    char* wsb = (char*)d_ws;
    size_t off = 0;
    auto carve = [&](size_t bytes) -> void* {
        void* p = wsb + off;
        off += (bytes + 255) & ~(size_t)255;
        return p;
    };
    int* ptr        = (int*)carve((size_t)(N + 1) * 4);
    int* cnt        = (int*)carve((size_t)N * 4);
    int* tilesum    = (int*)carve((size_t)ntiles * 4);
    int* edges      = (int*)carve((size_t)E * 4);
    int* ccnt       = (int*)carve((size_t)8 * nb * 4);
    uint2* binbuf   = (uint2*)carve((size_t)8 * nb * BIN_CAP * 8);
    ushort* WS1     = (ushort*)carve((size_t)256 * 768 * 2);
    ushort* WS2     = (ushort*)carve((size_t)256 * 384 * 2);
    ushort* WS3     = (ushort*)carve((size_t)256 * 384 * 2);
    ushort* WS4     = (ushort*)carve((size_t)256 * 384 * 2);
    ushort* tl_h    = (ushort*)carve((size_t)N * 128 * 2);   // neighbor-transform (fp16)
    float* tr_c     = (float*)carve((size_t)N * 128 * 4);    // root-transform (f32) / dec-v (fp16)
    ushort* A3      = (ushort*)carve((size_t)Npad * 512 * 2); // layer-1 [hi|lo]
    ushort* h3      = A3;                                     // reuse: [Npad][256]

    // ---- CSR build (binned, write-amplification-free) ----
    hipMemsetAsync(cnt, 0, (size_t)N * 4, stream);
    hipMemsetAsync(ccnt, 0, (size_t)8 * nb * 4, stream);
    count_kernel<<<(E + 255) / 256, 256, 0, stream>>>(dst, cnt, E);
    scanA_kernel<<<ntiles, 1024, 0, stream>>>(cnt, ptr, tilesum, N);
    scanB_kernel<<<1, 64, 0, stream>>>(tilesum, ptr, ntiles, N);
    scanC_kernel<<<(N + 255) / 256, 256, 0, stream>>>(ptr, tilesum, N);
    binA_kernel<<<1024, 256, 0, stream>>>(src, dst, ccnt, binbuf, nb, E);
    binB_kernel<<<nb, 256, 0, stream>>>(ccnt, binbuf, ptr, edges, nb);

    // ---- conversions ----
    convx_kernel<<<(N * 64 + 255) / 256, 256, 0, stream>>>(x, A3, N * 64);
    wprep_all_kernel<<<dim3(256, 4), 256, 0, stream>>>(w1l, w1r, w2l, w2r, w3l, w3r,
                                                       dw1, WS1, WS2, WS3, WS4);

    // ---- layer 1 ----
    mm_kernel<512, 0><<<nblk, 256, 0, stream>>>(A3, WS1, tl_h, tr_c, N);
    agg_kernel<<<(N + 3) / 4, 256, 0, stream>>>(tl_h, tr_c, ptr, edges, b1l,
                                                bn1g, bn1b, bn1m, bn1v, 1, h3, N);
    // ---- layer 2 ----
    mm_kernel<256, 0><<<nblk, 256, 0, stream>>>(h3, WS2, tl_h, tr_c, N);
    agg_kernel<<<(N + 3) / 4, 256, 0, stream>>>(tl_h, tr_c, ptr, edges, b2l,
                                                bn2g, bn2b, bn2m, bn2v, 1, h3, N);
    // ---- layer 3 (no BN) ----
    mm_kernel<256, 0><<<nblk, 256, 0, stream>>>(h3, WS3, tl_h, tr_c, N);
    agg_kernel<<<(N + 3) / 4, 256, 0, stream>>>(tl_h, tr_c, ptr, edges, b3l,
                                                bn1g, bn1b, bn1m, bn1v, 0, h3, N);
    // ---- decoder transforms u|v (both fp16), then pair decode ----
    mm_kernel<256, 1><<<nblk, 256, 0, stream>>>(h3, WS4, tl_h, tr_c, N);
    decode_kernel<<<(L + 255) / 256, 256, 0, stream>>>(tl_h, (const ushort*)tr_c, eli,
                                                       db1, dw2, db2, out, L);
}

// Round 10
// 405.586 us; speedup vs baseline: 1.0769x; 1.0769x over previous
//
#include <hip/hip_runtime.h>
#include <hip/hip_fp16.h>

// ---------------------------------------------------------------------------
// GraphSAGE (3x SAGEConv mean-agg + BN/ReLU) + link decoder.
// R10 changes vs R9:
//  - REVERT binned scatter (binA was atomic-latency bound, 70us > 58us).
//  - scatter rank-trick: count pass emits rank[i]=atomicAdd(cnt[dst],1);
//    scatter is atomic-free edges[ptr[d]+rank[i]]=src[i]. No cursor buffer.
//  - agg: __launch_bounds__(256,8) -> 2x occupancy (BW-vs-latency probe).
//  - mm / decode unchanged from R8.
// ---------------------------------------------------------------------------

typedef unsigned int uint;
using s16x8 = __attribute__((ext_vector_type(8))) short;
using f32x4 = __attribute__((ext_vector_type(4))) float;

__device__ inline void bsplit(float v, ushort& hi, ushort& lo) {
    // round-to-nearest-even bf16 split: v ~= hi + lo to ~2^-17 rel
    uint u = __float_as_uint(v);
    uint hb = (u + 0x7FFFu + ((u >> 16) & 1u)) >> 16;
    hi = (ushort)hb;
    float r = v - __uint_as_float(hb << 16);
    uint u2 = __float_as_uint(r);
    lo = (ushort)((u2 + 0x7FFFu + ((u2 >> 16) & 1u)) >> 16);
}

__device__ inline ushort f2h(float v) { return __half_as_ushort(__float2half(v)); }

__device__ inline float4 h4f(uint2 r) {
    float2 fa = __half22float2(*(const __half2*)&r.x);
    float2 fb = __half22float2(*(const __half2*)&r.y);
    return make_float4(fa.x, fa.y, fb.x, fb.y);
}

// swizzle a ushort index within its 64-ushort K-slice: chunk ^= (row&7)
__device__ inline uint swz(uint i, uint r) {
    return (i & ~63u) | ((i ^ (r << 3)) & 56u) | (i & 7u);
}

// async global->LDS, 16 bytes per lane
__device__ inline void gload16(const void* g, void* l) {
    __builtin_amdgcn_global_load_lds(
        (const __attribute__((address_space(1))) unsigned int*)g,
        (__attribute__((address_space(3))) unsigned int*)l, 16, 0, 0);
}

// ---------------- CSR build ----------------
// count + rank in one pass: rank[i] = arrival order of edge i at its dst
__global__ void count_kernel(const int* __restrict__ dst, int* __restrict__ cnt,
                             int* __restrict__ rank, int E) {
    int i = blockIdx.x * blockDim.x + threadIdx.x;
    if (i < E) rank[i] = atomicAdd(&cnt[dst[i]], 1);
}

__global__ void scanA_kernel(const int* __restrict__ cnt, int* __restrict__ ptr,
                             int* __restrict__ tilesum, int n) {
    __shared__ int sd[1024];
    int t = threadIdx.x;
    int i = blockIdx.x * 1024 + t;
    int v = (i < n) ? cnt[i] : 0;
    sd[t] = v;
    __syncthreads();
    #pragma unroll
    for (int off = 1; off < 1024; off <<= 1) {
        int add = (t >= off) ? sd[t - off] : 0;
        __syncthreads();
        sd[t] += add;
        __syncthreads();
    }
    if (i < n) ptr[i] = sd[t] - v;              // local exclusive
    if (t == 1023) tilesum[blockIdx.x] = sd[t]; // tile total
}

__global__ void scanB_kernel(int* __restrict__ tilesum, int* __restrict__ ptr,
                             int ntiles, int n) {
    if (threadIdx.x == 0 && blockIdx.x == 0) {
        int running = 0;
        for (int b = 0; b < ntiles; ++b) {
            int t = tilesum[b];
            tilesum[b] = running;
            running += t;
        }
        ptr[n] = running;
    }
}

__global__ void scanC_kernel(int* __restrict__ ptr, const int* __restrict__ tilesum, int n) {
    int i = blockIdx.x * blockDim.x + threadIdx.x;
    if (i < n) ptr[i] += tilesum[i >> 10];
}

// atomic-free scatter using precomputed ranks
__global__ void scatter_kernel(const int* __restrict__ src, const int* __restrict__ dst,
                               const int* __restrict__ ptr, const int* __restrict__ rank,
                               int* __restrict__ edges, int E) {
    int i = blockIdx.x * blockDim.x + threadIdx.x;
    if (i < E) edges[ptr[dst[i]] + rank[i]] = src[i];
}

// ---------------- conversions (pre-swizzled stores) ----------------
// A row (K=256): [hi(0..255) | lo(0..255)] (KP=512), chunk-swizzled per slice
__global__ __launch_bounds__(256) void convx_kernel(const float* __restrict__ x,
                                                    ushort* __restrict__ A3, int total) {
    int e = blockIdx.x * 256 + threadIdx.x;   // total = N*64 (float4 groups)
    if (e >= total) return;
    uint row = e >> 6;
    uint k4 = (e & 63) << 2;
    float4 v = *(const float4*)(x + (size_t)row * 256 + k4);
    ushort4 hi, lo;
    bsplit(v.x, hi.x, lo.x); bsplit(v.y, hi.y, lo.y);
    bsplit(v.z, hi.z, lo.z); bsplit(v.w, hi.w, lo.w);
    ushort* d = A3 + (size_t)row * 512;
    *(ushort4*)(d + swz(k4, row))       = hi;
    *(ushort4*)(d + swz(k4 + 256, row)) = lo;
}

// WS[n][k'] n-major, k' = [Wh | Wlo | Wh], chunk-swizzled per slice
__global__ void wprep_all_kernel(
    const float* __restrict__ w1l, const float* __restrict__ w1r,
    const float* __restrict__ w2l, const float* __restrict__ w2r,
    const float* __restrict__ w3l, const float* __restrict__ w3r,
    const float* __restrict__ dw1,
    ushort* __restrict__ WS1, ushort* __restrict__ WS2,
    ushort* __restrict__ WS3, ushort* __restrict__ WS4)
{
    int which = blockIdx.y;
    uint n = blockIdx.x;
    uint k = threadIdx.x;
    const float *wa, *wb;
    uint K, lda, aoff, boff;
    ushort* WS;
    switch (which) {
        case 0:  wa = w1l; wb = w1r; K = 256; lda = 256; aoff = 0; boff = 0;   WS = WS1; break;
        case 1:  wa = w2l; wb = w2r; K = 128; lda = 128; aoff = 0; boff = 0;   WS = WS2; break;
        case 2:  wa = w3l; wb = w3r; K = 128; lda = 128; aoff = 0; boff = 0;   WS = WS3; break;
        default: wa = dw1; wb = dw1; K = 128; lda = 256; aoff = 0; boff = 128; WS = WS4; break;
    }
    if (k >= K) return;
    const float* srcr = (n < 128) ? (wa + (size_t)n * lda + aoff)
                                  : (wb + (size_t)(n - 128) * lda + boff);
    ushort hi, lo;
    bsplit(srcr[k], hi, lo);
    ushort* d = WS + (size_t)n * 3 * K;
    d[swz(k, n)]         = hi;
    d[swz(K + k, n)]     = lo;
    d[swz(2 * K + k, n)] = hi;
}

// ---------------- MFMA GEMM ----------------
// Block = 128 rows x 256 cols. 4 waves, each 64x128.
// A[M][KP] = [hi|lo] pre-swizzled; W[256][KP*3/2] = [Wh|Wlo|Wh] pre-swizzled.
// Staging = global_load_lds 16B into LINEAR LDS; ds_read applies the XOR.
// Cl (cols 0..127) written fp16; Cr written fp16 iff CRF16 else f32.
template <int KP, int CRF16>
__global__ __launch_bounds__(256, 2) void mm_kernel(const ushort* __restrict__ A,
                                                    const ushort* __restrict__ WS,
                                                    ushort* __restrict__ Cl,
                                                    void* __restrict__ Cr_, int M) {
    constexpr int KS  = (KP / 64) + (KP / 128);   // 12 (KP=512) or 6 (KP=256)
    constexpr int WKP = KP + KP / 2;
    __shared__ ushort At[128 * 64];
    __shared__ ushort Bt[256 * 64];
    const int t = threadIdx.x;
    const int lane = t & 63;
    const int wave = t >> 6;
    const int wm = wave >> 1, wn = wave & 1;      // 2 row-halves x 2 col-halves
    const int row0 = blockIdx.x * 128;
    const int l15 = lane & 15;
    const int l4 = lane >> 4;
    const int l8 = lane >> 3;                     // staging row within 8-row group
    const int c8 = lane & 7;                      // staging chunk within row

    f32x4 acc[4][8] = {};

    for (int s = 0; s < KS; ++s) {
        const int as = (s < KP / 128) ? s : s - (KP / 128);
        #pragma unroll
        for (int j = 0; j < 4; ++j) {
            int jj = wave + j * 4;                // A group 0..15
            int r = jj * 8 + l8;
            gload16(A + (size_t)(row0 + r) * KP + as * 64 + c8 * 8,
                    (char*)At + jj * 1024 + lane * 16);
        }
        #pragma unroll
        for (int j = 0; j < 8; ++j) {
            int jj = wave + j * 4;                // B group 0..31
            int r = jj * 8 + l8;
            gload16(WS + (size_t)r * WKP + s * 64 + c8 * 8,
                    (char*)Bt + jj * 1024 + lane * 16);
        }
        __syncthreads();
        #pragma unroll
        for (int kk = 0; kk < 64; kk += 32) {
            s16x8 af[4], bf[8];
            #pragma unroll
            for (int mi = 0; mi < 4; ++mi) {
                int r = wm * 64 + mi * 16 + l15;
                int off = (kk + l4 * 8) ^ ((r & 7) * 8);
                af[mi] = *(const s16x8*)&At[r * 64 + off];
            }
            #pragma unroll
            for (int ni = 0; ni < 8; ++ni) {
                int r = wn * 128 + ni * 16 + l15;
                int off = (kk + l4 * 8) ^ ((r & 7) * 8);
                bf[ni] = *(const s16x8*)&Bt[r * 64 + off];
            }
            #pragma unroll
            for (int mi = 0; mi < 4; ++mi)
                #pragma unroll
                for (int ni = 0; ni < 8; ++ni)
                    acc[mi][ni] = __builtin_amdgcn_mfma_f32_16x16x32_bf16(
                        af[mi], bf[ni], acc[mi][ni], 0, 0, 0);
        }
        __syncthreads();
    }
    // ---- epilogue: row = (lane>>4)*4+j, col = lane&15 within 16x16
    #pragma unroll
    for (int mi = 0; mi < 4; ++mi) {
        int rbase = row0 + wm * 64 + mi * 16 + l4 * 4;
        #pragma unroll
        for (int ni = 0; ni < 8; ++ni) {
            int col = ni * 16 + l15;
            #pragma unroll
            for (int j = 0; j < 4; ++j) {
                int r = rbase + j;
                if (r < M) {
                    if (wn == 0) {
                        Cl[(size_t)r * 128 + col] = f2h(acc[mi][ni][j]);
                    } else if (CRF16) {
                        ((ushort*)Cr_)[(size_t)r * 128 + col] = f2h(acc[mi][ni][j]);
                    } else {
                        ((float*)Cr_)[(size_t)r * 128 + col] = acc[mi][ni][j];
                    }
                }
            }
        }
    }
}

// ---------------- aggregation ----------------
// One node per wave; lanes 0-31 even edge slots, 32-63 odd; shfl_xor combine.
// tl is fp16 (256B/row gathers); root tr is f32 (streamed).
// out = opt_bn_relu( mean tl[src] + bl + tr[i] ), emits h[n][256]=[hi|lo] swz.
__global__ __launch_bounds__(256, 8) void agg_kernel(
    const ushort* __restrict__ tl, const float* __restrict__ tr,
    const int* __restrict__ ptr, const int* __restrict__ edges,
    const float* __restrict__ bl,
    const float* __restrict__ bng, const float* __restrict__ bnb,
    const float* __restrict__ bnm, const float* __restrict__ bnv,
    int do_bn, ushort* __restrict__ h3, int n) {
    const int wave = threadIdx.x >> 6;
    const int lane = threadIdx.x & 63;
    const uint node = blockIdx.x * 4 + wave;
    if (node >= (uint)n) return;
    const int half = lane >> 5;
    const uint q4 = (lane & 31) << 2;             // 4 feats per lane
    const int p0 = ptr[node], p1 = ptr[node + 1];
    float4 a0 = make_float4(0.f, 0.f, 0.f, 0.f), a1 = a0, a2 = a0, a3 = a0;
    float4 a4 = a0, a5 = a0, a6 = a0, a7 = a0;
    int e = p0 + half;
    for (; e + 14 < p1; e += 16) {                // 8 edges per half per iter
        int i0 = edges[e],      i1 = edges[e + 2],  i2 = edges[e + 4],  i3 = edges[e + 6];
        int i4 = edges[e + 8],  i5 = edges[e + 10], i6 = edges[e + 12], i7 = edges[e + 14];
        uint2 r0 = *(const uint2*)(tl + (size_t)i0 * 128 + q4);
        uint2 r1 = *(const uint2*)(tl + (size_t)i1 * 128 + q4);
        uint2 r2 = *(const uint2*)(tl + (size_t)i2 * 128 + q4);
        uint2 r3 = *(const uint2*)(tl + (size_t)i3 * 128 + q4);
        uint2 r4 = *(const uint2*)(tl + (size_t)i4 * 128 + q4);
        uint2 r5 = *(const uint2*)(tl + (size_t)i5 * 128 + q4);
        uint2 r6 = *(const uint2*)(tl + (size_t)i6 * 128 + q4);
        uint2 r7 = *(const uint2*)(tl + (size_t)i7 * 128 + q4);
        float4 v0 = h4f(r0), v1 = h4f(r1), v2 = h4f(r2), v3 = h4f(r3);
        float4 v4 = h4f(r4), v5 = h4f(r5), v6 = h4f(r6), v7 = h4f(r7);
        a0.x += v0.x; a0.y += v0.y; a0.z += v0.z; a0.w += v0.w;
        a1.x += v1.x; a1.y += v1.y; a1.z += v1.z; a1.w += v1.w;
        a2.x += v2.x; a2.y += v2.y; a2.z += v2.z; a2.w += v2.w;
        a3.x += v3.x; a3.y += v3.y; a3.z += v3.z; a3.w += v3.w;
        a4.x += v4.x; a4.y += v4.y; a4.z += v4.z; a4.w += v4.w;
        a5.x += v5.x; a5.y += v5.y; a5.z += v5.z; a5.w += v5.w;
        a6.x += v6.x; a6.y += v6.y; a6.z += v6.z; a6.w += v6.w;
        a7.x += v7.x; a7.y += v7.y; a7.z += v7.z; a7.w += v7.w;
    }
    for (; e < p1; e += 2) {
        int i0 = edges[e];
        float4 v0 = h4f(*(const uint2*)(tl + (size_t)i0 * 128 + q4));
        a0.x += v0.x; a0.y += v0.y; a0.z += v0.z; a0.w += v0.w;
    }
    float4 s;
    s.x = ((a0.x + a1.x) + (a2.x + a3.x)) + ((a4.x + a5.x) + (a6.x + a7.x));
    s.y = ((a0.y + a1.y) + (a2.y + a3.y)) + ((a4.y + a5.y) + (a6.y + a7.y));
    s.z = ((a0.z + a1.z) + (a2.z + a3.z)) + ((a4.z + a5.z) + (a6.z + a7.z));
    s.w = ((a0.w + a1.w) + (a2.w + a3.w)) + ((a4.w + a5.w) + (a6.w + a7.w));
    // combine even/odd halves (lane <-> lane^32)
    s.x += __shfl_xor(s.x, 32);
    s.y += __shfl_xor(s.y, 32);
    s.z += __shfl_xor(s.z, 32);
    s.w += __shfl_xor(s.w, 32);
    if (half == 0) {
        float inv = 1.f / fmaxf((float)(p1 - p0), 1.f);
        float4 r = *(const float4*)(tr + (size_t)node * 128 + q4);
        float4 b = *(const float4*)(bl + q4);
        float4 val;
        val.x = fmaf(s.x, inv, b.x) + r.x;
        val.y = fmaf(s.y, inv, b.y) + r.y;
        val.z = fmaf(s.z, inv, b.z) + r.z;
        val.w = fmaf(s.w, inv, b.w) + r.w;
        if (do_bn) {
            float4 g = *(const float4*)(bng + q4);
            float4 be = *(const float4*)(bnb + q4);
            float4 m = *(const float4*)(bnm + q4);
            float4 vv = *(const float4*)(bnv + q4);
            val.x = fmaxf(fmaf(val.x - m.x, g.x * rsqrtf(vv.x + 1e-5f), be.x), 0.f);
            val.y = fmaxf(fmaf(val.y - m.y, g.y * rsqrtf(vv.y + 1e-5f), be.y), 0.f);
            val.z = fmaxf(fmaf(val.z - m.z, g.z * rsqrtf(vv.z + 1e-5f), be.z), 0.f);
            val.w = fmaxf(fmaf(val.w - m.w, g.w * rsqrtf(vv.w + 1e-5f), be.w), 0.f);
        }
        ushort4 hi, lo;
        bsplit(val.x, hi.x, lo.x); bsplit(val.y, hi.y, lo.y);
        bsplit(val.z, hi.z, lo.z); bsplit(val.w, hi.w, lo.w);
        ushort* d = h3 + (size_t)node * 256;
        *(ushort4*)(d + swz(q4, node))       = hi;
        *(ushort4*)(d + swz(q4 + 128, node)) = lo;
    }
}

// ---------------- decoder: relu(u[s] + v[d] + b) . w2 + b2 (u,v fp16) -------
__global__ __launch_bounds__(256) void decode_kernel(
    const ushort* __restrict__ u, const ushort* __restrict__ v,
    const int* __restrict__ eli, const float* __restrict__ db1,
    const float* __restrict__ dw2, const float* __restrict__ db2,
    float* __restrict__ out, int L) {
    __shared__ float sb[128], sw[128];
    if (threadIdx.x < 128) {
        sb[threadIdx.x] = db1[threadIdx.x];
        sw[threadIdx.x] = dw2[threadIdx.x];
    }
    __syncthreads();
    int p = blockIdx.x * 256 + threadIdx.x;
    if (p >= L) return;
    int s = eli[p], d = eli[L + p];
    const ushort* up = u + (size_t)s * 128;
    const ushort* vp = v + (size_t)d * 128;
    float acc = db2[0];
    #pragma unroll 8
    for (int o = 0; o < 128; o += 4) {
        float4 a = h4f(*(const uint2*)(up + o));
        float4 b = h4f(*(const uint2*)(vp + o));
        float4 bb = *(const float4*)(&sb[o]);
        float4 w = *(const float4*)(&sw[o]);
        acc += fmaxf(a.x + b.x + bb.x, 0.f) * w.x;
        acc += fmaxf(a.y + b.y + bb.y, 0.f) * w.y;
        acc += fmaxf(a.z + b.z + bb.z, 0.f) * w.z;
        acc += fmaxf(a.w + b.w + bb.w, 0.f) * w.w;
    }
    out[p] = acc;
}

extern "C" void kernel_launch(void* const* d_in, const int* in_sizes, int n_in,
                              void* d_out, int out_size, void* d_ws, size_t ws_size,
                              hipStream_t stream) {
    const float* x    = (const float*)d_in[0];
    const int*   ei   = (const int*)d_in[1];
    const int*   eli  = (const int*)d_in[2];
    const float* w1l  = (const float*)d_in[3];
    const float* b1l  = (const float*)d_in[4];
    const float* w1r  = (const float*)d_in[5];
    const float* w2l  = (const float*)d_in[6];
    const float* b2l  = (const float*)d_in[7];
    const float* w2r  = (const float*)d_in[8];
    const float* w3l  = (const float*)d_in[9];
    const float* b3l  = (const float*)d_in[10];
    const float* w3r  = (const float*)d_in[11];
    const float* bn1g = (const float*)d_in[12];
    const float* bn1b = (const float*)d_in[13];
    const float* bn1m = (const float*)d_in[14];
    const float* bn1v = (const float*)d_in[15];
    const float* bn2g = (const float*)d_in[16];
    const float* bn2b = (const float*)d_in[17];
    const float* bn2m = (const float*)d_in[18];
    const float* bn2v = (const float*)d_in[19];
    const float* dw1  = (const float*)d_in[20];
    const float* db1  = (const float*)d_in[21];
    const float* dw2  = (const float*)d_in[22];
    const float* db2  = (const float*)d_in[23];
    float* out = (float*)d_out;

    const int N = in_sizes[0] / 256;
    const int E = in_sizes[1] / 2;
    const int L = in_sizes[2] / 2;
    const int* src = ei;
    const int* dst = ei + E;
    const int ntiles = (N + 1023) >> 10;
    const int nblk = (N + 127) / 128;
    const int Npad = nblk * 128;

    char* wsb = (char*)d_ws;
    size_t off = 0;
    auto carve = [&](size_t bytes) -> void* {
        void* p = wsb + off;
        off += (bytes + 255) & ~(size_t)255;
        return p;
    };
    int* ptr        = (int*)carve((size_t)(N + 1) * 4);
    int* cnt        = (int*)carve((size_t)N * 4);
    int* rank       = (int*)carve((size_t)E * 4);
    int* tilesum    = (int*)carve((size_t)ntiles * 4);
    int* edges      = (int*)carve((size_t)E * 4);
    ushort* WS1     = (ushort*)carve((size_t)256 * 768 * 2);
    ushort* WS2     = (ushort*)carve((size_t)256 * 384 * 2);
    ushort* WS3     = (ushort*)carve((size_t)256 * 384 * 2);
    ushort* WS4     = (ushort*)carve((size_t)256 * 384 * 2);
    ushort* tl_h    = (ushort*)carve((size_t)N * 128 * 2);   // neighbor-transform (fp16)
    float* tr_c     = (float*)carve((size_t)N * 128 * 4);    // root-transform (f32) / dec-v (fp16)
    ushort* A3      = (ushort*)carve((size_t)Npad * 512 * 2); // layer-1 [hi|lo]
    ushort* h3      = A3;                                     // reuse: [Npad][256]

    // ---- CSR build (count+rank, scan, atomic-free scatter) ----
    hipMemsetAsync(cnt, 0, (size_t)N * 4, stream);
    count_kernel<<<(E + 255) / 256, 256, 0, stream>>>(dst, cnt, rank, E);
    scanA_kernel<<<ntiles, 1024, 0, stream>>>(cnt, ptr, tilesum, N);
    scanB_kernel<<<1, 64, 0, stream>>>(tilesum, ptr, ntiles, N);
    scanC_kernel<<<(N + 255) / 256, 256, 0, stream>>>(ptr, tilesum, N);
    scatter_kernel<<<(E + 255) / 256, 256, 0, stream>>>(src, dst, ptr, rank, edges, E);

    // ---- conversions ----
    convx_kernel<<<(N * 64 + 255) / 256, 256, 0, stream>>>(x, A3, N * 64);
    wprep_all_kernel<<<dim3(256, 4), 256, 0, stream>>>(w1l, w1r, w2l, w2r, w3l, w3r,
                                                       dw1, WS1, WS2, WS3, WS4);

    // ---- layer 1 ----
    mm_kernel<512, 0><<<nblk, 256, 0, stream>>>(A3, WS1, tl_h, tr_c, N);
    agg_kernel<<<(N + 3) / 4, 256, 0, stream>>>(tl_h, tr_c, ptr, edges, b1l,
                                                bn1g, bn1b, bn1m, bn1v, 1, h3, N);
    // ---- layer 2 ----
    mm_kernel<256, 0><<<nblk, 256, 0, stream>>>(h3, WS2, tl_h, tr_c, N);
    agg_kernel<<<(N + 3) / 4, 256, 0, stream>>>(tl_h, tr_c, ptr, edges, b2l,
                                                bn2g, bn2b, bn2m, bn2v, 1, h3, N);
    // ---- layer 3 (no BN) ----
    mm_kernel<256, 0><<<nblk, 256, 0, stream>>>(h3, WS3, tl_h, tr_c, N);
    agg_kernel<<<(N + 3) / 4, 256, 0, stream>>>(tl_h, tr_c, ptr, edges, b3l,
                                                bn1g, bn1b, bn1m, bn1v, 0, h3, N);
    // ---- decoder transforms u|v (both fp16), then pair decode ----
    mm_kernel<256, 1><<<nblk, 256, 0, stream>>>(h3, WS4, tl_h, tr_c, N);
    decode_kernel<<<(L + 255) / 256, 256, 0, stream>>>(tl_h, (const ushort*)tr_c, eli,
                                                       db1, dw2, db2, out, L);
}

// Round 11
// 366.472 us; speedup vs baseline: 1.1918x; 1.1067x over previous
//
#include <hip/hip_runtime.h>
#include <hip/hip_fp16.h>

// ---------------------------------------------------------------------------
// GraphSAGE (3x SAGEConv mean-agg + BN/ReLU) + link decoder.
// R11 = R10 with agg reverted to __launch_bounds__(256,4):
//  R10's (256,8) probe showed agg is CACHE-CAPACITY-bound: 2x waves ->
//  FETCH +54%, WRITE 5x (L2 thrash), dur 55.7->79us. 4 blocks/CU is optimal.
//  Keeps R10's rank-trick scatter (atomic-free, ~57us faster CSR path).
// ---------------------------------------------------------------------------

typedef unsigned int uint;
using s16x8 = __attribute__((ext_vector_type(8))) short;
using f32x4 = __attribute__((ext_vector_type(4))) float;

__device__ inline void bsplit(float v, ushort& hi, ushort& lo) {
    // round-to-nearest-even bf16 split: v ~= hi + lo to ~2^-17 rel
    uint u = __float_as_uint(v);
    uint hb = (u + 0x7FFFu + ((u >> 16) & 1u)) >> 16;
    hi = (ushort)hb;
    float r = v - __uint_as_float(hb << 16);
    uint u2 = __float_as_uint(r);
    lo = (ushort)((u2 + 0x7FFFu + ((u2 >> 16) & 1u)) >> 16);
}

__device__ inline ushort f2h(float v) { return __half_as_ushort(__float2half(v)); }

__device__ inline float4 h4f(uint2 r) {
    float2 fa = __half22float2(*(const __half2*)&r.x);
    float2 fb = __half22float2(*(const __half2*)&r.y);
    return make_float4(fa.x, fa.y, fb.x, fb.y);
}

// swizzle a ushort index within its 64-ushort K-slice: chunk ^= (row&7)
__device__ inline uint swz(uint i, uint r) {
    return (i & ~63u) | ((i ^ (r << 3)) & 56u) | (i & 7u);
}

// async global->LDS, 16 bytes per lane
__device__ inline void gload16(const void* g, void* l) {
    __builtin_amdgcn_global_load_lds(
        (const __attribute__((address_space(1))) unsigned int*)g,
        (__attribute__((address_space(3))) unsigned int*)l, 16, 0, 0);
}

// ---------------- CSR build ----------------
// count + rank in one pass: rank[i] = arrival order of edge i at its dst
__global__ void count_kernel(const int* __restrict__ dst, int* __restrict__ cnt,
                             int* __restrict__ rank, int E) {
    int i = blockIdx.x * blockDim.x + threadIdx.x;
    if (i < E) rank[i] = atomicAdd(&cnt[dst[i]], 1);
}

__global__ void scanA_kernel(const int* __restrict__ cnt, int* __restrict__ ptr,
                             int* __restrict__ tilesum, int n) {
    __shared__ int sd[1024];
    int t = threadIdx.x;
    int i = blockIdx.x * 1024 + t;
    int v = (i < n) ? cnt[i] : 0;
    sd[t] = v;
    __syncthreads();
    #pragma unroll
    for (int off = 1; off < 1024; off <<= 1) {
        int add = (t >= off) ? sd[t - off] : 0;
        __syncthreads();
        sd[t] += add;
        __syncthreads();
    }
    if (i < n) ptr[i] = sd[t] - v;              // local exclusive
    if (t == 1023) tilesum[blockIdx.x] = sd[t]; // tile total
}

__global__ void scanB_kernel(int* __restrict__ tilesum, int* __restrict__ ptr,
                             int ntiles, int n) {
    if (threadIdx.x == 0 && blockIdx.x == 0) {
        int running = 0;
        for (int b = 0; b < ntiles; ++b) {
            int t = tilesum[b];
            tilesum[b] = running;
            running += t;
        }
        ptr[n] = running;
    }
}

__global__ void scanC_kernel(int* __restrict__ ptr, const int* __restrict__ tilesum, int n) {
    int i = blockIdx.x * blockDim.x + threadIdx.x;
    if (i < n) ptr[i] += tilesum[i >> 10];
}

// atomic-free scatter using precomputed ranks
__global__ void scatter_kernel(const int* __restrict__ src, const int* __restrict__ dst,
                               const int* __restrict__ ptr, const int* __restrict__ rank,
                               int* __restrict__ edges, int E) {
    int i = blockIdx.x * blockDim.x + threadIdx.x;
    if (i < E) edges[ptr[dst[i]] + rank[i]] = src[i];
}

// ---------------- conversions (pre-swizzled stores) ----------------
// A row (K=256): [hi(0..255) | lo(0..255)] (KP=512), chunk-swizzled per slice
__global__ __launch_bounds__(256) void convx_kernel(const float* __restrict__ x,
                                                    ushort* __restrict__ A3, int total) {
    int e = blockIdx.x * 256 + threadIdx.x;   // total = N*64 (float4 groups)
    if (e >= total) return;
    uint row = e >> 6;
    uint k4 = (e & 63) << 2;
    float4 v = *(const float4*)(x + (size_t)row * 256 + k4);
    ushort4 hi, lo;
    bsplit(v.x, hi.x, lo.x); bsplit(v.y, hi.y, lo.y);
    bsplit(v.z, hi.z, lo.z); bsplit(v.w, hi.w, lo.w);
    ushort* d = A3 + (size_t)row * 512;
    *(ushort4*)(d + swz(k4, row))       = hi;
    *(ushort4*)(d + swz(k4 + 256, row)) = lo;
}

// WS[n][k'] n-major, k' = [Wh | Wlo | Wh], chunk-swizzled per slice
__global__ void wprep_all_kernel(
    const float* __restrict__ w1l, const float* __restrict__ w1r,
    const float* __restrict__ w2l, const float* __restrict__ w2r,
    const float* __restrict__ w3l, const float* __restrict__ w3r,
    const float* __restrict__ dw1,
    ushort* __restrict__ WS1, ushort* __restrict__ WS2,
    ushort* __restrict__ WS3, ushort* __restrict__ WS4)
{
    int which = blockIdx.y;
    uint n = blockIdx.x;
    uint k = threadIdx.x;
    const float *wa, *wb;
    uint K, lda, aoff, boff;
    ushort* WS;
    switch (which) {
        case 0:  wa = w1l; wb = w1r; K = 256; lda = 256; aoff = 0; boff = 0;   WS = WS1; break;
        case 1:  wa = w2l; wb = w2r; K = 128; lda = 128; aoff = 0; boff = 0;   WS = WS2; break;
        case 2:  wa = w3l; wb = w3r; K = 128; lda = 128; aoff = 0; boff = 0;   WS = WS3; break;
        default: wa = dw1; wb = dw1; K = 128; lda = 256; aoff = 0; boff = 128; WS = WS4; break;
    }
    if (k >= K) return;
    const float* srcr = (n < 128) ? (wa + (size_t)n * lda + aoff)
                                  : (wb + (size_t)(n - 128) * lda + boff);
    ushort hi, lo;
    bsplit(srcr[k], hi, lo);
    ushort* d = WS + (size_t)n * 3 * K;
    d[swz(k, n)]         = hi;
    d[swz(K + k, n)]     = lo;
    d[swz(2 * K + k, n)] = hi;
}

// ---------------- MFMA GEMM ----------------
// Block = 128 rows x 256 cols. 4 waves, each 64x128.
// A[M][KP] = [hi|lo] pre-swizzled; W[256][KP*3/2] = [Wh|Wlo|Wh] pre-swizzled.
// Staging = global_load_lds 16B into LINEAR LDS; ds_read applies the XOR.
// Cl (cols 0..127) written fp16; Cr written fp16 iff CRF16 else f32.
template <int KP, int CRF16>
__global__ __launch_bounds__(256, 2) void mm_kernel(const ushort* __restrict__ A,
                                                    const ushort* __restrict__ WS,
                                                    ushort* __restrict__ Cl,
                                                    void* __restrict__ Cr_, int M) {
    constexpr int KS  = (KP / 64) + (KP / 128);   // 12 (KP=512) or 6 (KP=256)
    constexpr int WKP = KP + KP / 2;
    __shared__ ushort At[128 * 64];
    __shared__ ushort Bt[256 * 64];
    const int t = threadIdx.x;
    const int lane = t & 63;
    const int wave = t >> 6;
    const int wm = wave >> 1, wn = wave & 1;      // 2 row-halves x 2 col-halves
    const int row0 = blockIdx.x * 128;
    const int l15 = lane & 15;
    const int l4 = lane >> 4;
    const int l8 = lane >> 3;                     // staging row within 8-row group
    const int c8 = lane & 7;                      // staging chunk within row

    f32x4 acc[4][8] = {};

    for (int s = 0; s < KS; ++s) {
        const int as = (s < KP / 128) ? s : s - (KP / 128);
        #pragma unroll
        for (int j = 0; j < 4; ++j) {
            int jj = wave + j * 4;                // A group 0..15
            int r = jj * 8 + l8;
            gload16(A + (size_t)(row0 + r) * KP + as * 64 + c8 * 8,
                    (char*)At + jj * 1024 + lane * 16);
        }
        #pragma unroll
        for (int j = 0; j < 8; ++j) {
            int jj = wave + j * 4;                // B group 0..31
            int r = jj * 8 + l8;
            gload16(WS + (size_t)r * WKP + s * 64 + c8 * 8,
                    (char*)Bt + jj * 1024 + lane * 16);
        }
        __syncthreads();
        #pragma unroll
        for (int kk = 0; kk < 64; kk += 32) {
            s16x8 af[4], bf[8];
            #pragma unroll
            for (int mi = 0; mi < 4; ++mi) {
                int r = wm * 64 + mi * 16 + l15;
                int off = (kk + l4 * 8) ^ ((r & 7) * 8);
                af[mi] = *(const s16x8*)&At[r * 64 + off];
            }
            #pragma unroll
            for (int ni = 0; ni < 8; ++ni) {
                int r = wn * 128 + ni * 16 + l15;
                int off = (kk + l4 * 8) ^ ((r & 7) * 8);
                bf[ni] = *(const s16x8*)&Bt[r * 64 + off];
            }
            #pragma unroll
            for (int mi = 0; mi < 4; ++mi)
                #pragma unroll
                for (int ni = 0; ni < 8; ++ni)
                    acc[mi][ni] = __builtin_amdgcn_mfma_f32_16x16x32_bf16(
                        af[mi], bf[ni], acc[mi][ni], 0, 0, 0);
        }
        __syncthreads();
    }
    // ---- epilogue: row = (lane>>4)*4+j, col = lane&15 within 16x16
    #pragma unroll
    for (int mi = 0; mi < 4; ++mi) {
        int rbase = row0 + wm * 64 + mi * 16 + l4 * 4;
        #pragma unroll
        for (int ni = 0; ni < 8; ++ni) {
            int col = ni * 16 + l15;
            #pragma unroll
            for (int j = 0; j < 4; ++j) {
                int r = rbase + j;
                if (r < M) {
                    if (wn == 0) {
                        Cl[(size_t)r * 128 + col] = f2h(acc[mi][ni][j]);
                    } else if (CRF16) {
                        ((ushort*)Cr_)[(size_t)r * 128 + col] = f2h(acc[mi][ni][j]);
                    } else {
                        ((float*)Cr_)[(size_t)r * 128 + col] = acc[mi][ni][j];
                    }
                }
            }
        }
    }
}

// ---------------- aggregation ----------------
// One node per wave; lanes 0-31 even edge slots, 32-63 odd; shfl_xor combine.
// tl is fp16 (256B/row gathers); root tr is f32 (streamed).
// out = opt_bn_relu( mean tl[src] + bl + tr[i] ), emits h[n][256]=[hi|lo] swz.
__global__ __launch_bounds__(256, 4) void agg_kernel(
    const ushort* __restrict__ tl, const float* __restrict__ tr,
    const int* __restrict__ ptr, const int* __restrict__ edges,
    const float* __restrict__ bl,
    const float* __restrict__ bng, const float* __restrict__ bnb,
    const float* __restrict__ bnm, const float* __restrict__ bnv,
    int do_bn, ushort* __restrict__ h3, int n) {
    const int wave = threadIdx.x >> 6;
    const int lane = threadIdx.x & 63;
    const uint node = blockIdx.x * 4 + wave;
    if (node >= (uint)n) return;
    const int half = lane >> 5;
    const uint q4 = (lane & 31) << 2;             // 4 feats per lane
    const int p0 = ptr[node], p1 = ptr[node + 1];
    float4 a0 = make_float4(0.f, 0.f, 0.f, 0.f), a1 = a0, a2 = a0, a3 = a0;
    float4 a4 = a0, a5 = a0, a6 = a0, a7 = a0;
    int e = p0 + half;
    for (; e + 14 < p1; e += 16) {                // 8 edges per half per iter
        int i0 = edges[e],      i1 = edges[e + 2],  i2 = edges[e + 4],  i3 = edges[e + 6];
        int i4 = edges[e + 8],  i5 = edges[e + 10], i6 = edges[e + 12], i7 = edges[e + 14];
        uint2 r0 = *(const uint2*)(tl + (size_t)i0 * 128 + q4);
        uint2 r1 = *(const uint2*)(tl + (size_t)i1 * 128 + q4);
        uint2 r2 = *(const uint2*)(tl + (size_t)i2 * 128 + q4);
        uint2 r3 = *(const uint2*)(tl + (size_t)i3 * 128 + q4);
        uint2 r4 = *(const uint2*)(tl + (size_t)i4 * 128 + q4);
        uint2 r5 = *(const uint2*)(tl + (size_t)i5 * 128 + q4);
        uint2 r6 = *(const uint2*)(tl + (size_t)i6 * 128 + q4);
        uint2 r7 = *(const uint2*)(tl + (size_t)i7 * 128 + q4);
        float4 v0 = h4f(r0), v1 = h4f(r1), v2 = h4f(r2), v3 = h4f(r3);
        float4 v4 = h4f(r4), v5 = h4f(r5), v6 = h4f(r6), v7 = h4f(r7);
        a0.x += v0.x; a0.y += v0.y; a0.z += v0.z; a0.w += v0.w;
        a1.x += v1.x; a1.y += v1.y; a1.z += v1.z; a1.w += v1.w;
        a2.x += v2.x; a2.y += v2.y; a2.z += v2.z; a2.w += v2.w;
        a3.x += v3.x; a3.y += v3.y; a3.z += v3.z; a3.w += v3.w;
        a4.x += v4.x; a4.y += v4.y; a4.z += v4.z; a4.w += v4.w;
        a5.x += v5.x; a5.y += v5.y; a5.z += v5.z; a5.w += v5.w;
        a6.x += v6.x; a6.y += v6.y; a6.z += v6.z; a6.w += v6.w;
        a7.x += v7.x; a7.y += v7.y; a7.z += v7.z; a7.w += v7.w;
    }
    for (; e < p1; e += 2) {
        int i0 = edges[e];
        float4 v0 = h4f(*(const uint2*)(tl + (size_t)i0 * 128 + q4));
        a0.x += v0.x; a0.y += v0.y; a0.z += v0.z; a0.w += v0.w;
    }
    float4 s;
    s.x = ((a0.x + a1.x) + (a2.x + a3.x)) + ((a4.x + a5.x) + (a6.x + a7.x));
    s.y = ((a0.y + a1.y) + (a2.y + a3.y)) + ((a4.y + a5.y) + (a6.y + a7.y));
    s.z = ((a0.z + a1.z) + (a2.z + a3.z)) + ((a4.z + a5.z) + (a6.z + a7.z));
    s.w = ((a0.w + a1.w) + (a2.w + a3.w)) + ((a4.w + a5.w) + (a6.w + a7.w));
    // combine even/odd halves (lane <-> lane^32)
    s.x += __shfl_xor(s.x, 32);
    s.y += __shfl_xor(s.y, 32);
    s.z += __shfl_xor(s.z, 32);
    s.w += __shfl_xor(s.w, 32);
    if (half == 0) {
        float inv = 1.f / fmaxf((float)(p1 - p0), 1.f);
        float4 r = *(const float4*)(tr + (size_t)node * 128 + q4);
        float4 b = *(const float4*)(bl + q4);
        float4 val;
        val.x = fmaf(s.x, inv, b.x) + r.x;
        val.y = fmaf(s.y, inv, b.y) + r.y;
        val.z = fmaf(s.z, inv, b.z) + r.z;
        val.w = fmaf(s.w, inv, b.w) + r.w;
        if (do_bn) {
            float4 g = *(const float4*)(bng + q4);
            float4 be = *(const float4*)(bnb + q4);
            float4 m = *(const float4*)(bnm + q4);
            float4 vv = *(const float4*)(bnv + q4);
            val.x = fmaxf(fmaf(val.x - m.x, g.x * rsqrtf(vv.x + 1e-5f), be.x), 0.f);
            val.y = fmaxf(fmaf(val.y - m.y, g.y * rsqrtf(vv.y + 1e-5f), be.y), 0.f);
            val.z = fmaxf(fmaf(val.z - m.z, g.z * rsqrtf(vv.z + 1e-5f), be.z), 0.f);
            val.w = fmaxf(fmaf(val.w - m.w, g.w * rsqrtf(vv.w + 1e-5f), be.w), 0.f);
        }
        ushort4 hi, lo;
        bsplit(val.x, hi.x, lo.x); bsplit(val.y, hi.y, lo.y);
        bsplit(val.z, hi.z, lo.z); bsplit(val.w, hi.w, lo.w);
        ushort* d = h3 + (size_t)node * 256;
        *(ushort4*)(d + swz(q4, node))       = hi;
        *(ushort4*)(d + swz(q4 + 128, node)) = lo;
    }
}

// ---------------- decoder: relu(u[s] + v[d] + b) . w2 + b2 (u,v fp16) -------
__global__ __launch_bounds__(256) void decode_kernel(
    const ushort* __restrict__ u, const ushort* __restrict__ v,
    const int* __restrict__ eli, const float* __restrict__ db1,
    const float* __restrict__ dw2, const float* __restrict__ db2,
    float* __restrict__ out, int L) {
    __shared__ float sb[128], sw[128];
    if (threadIdx.x < 128) {
        sb[threadIdx.x] = db1[threadIdx.x];
        sw[threadIdx.x] = dw2[threadIdx.x];
    }
    __syncthreads();
    int p = blockIdx.x * 256 + threadIdx.x;
    if (p >= L) return;
    int s = eli[p], d = eli[L + p];
    const ushort* up = u + (size_t)s * 128;
    const ushort* vp = v + (size_t)d * 128;
    float acc = db2[0];
    #pragma unroll 8
    for (int o = 0; o < 128; o += 4) {
        float4 a = h4f(*(const uint2*)(up + o));
        float4 b = h4f(*(const uint2*)(vp + o));
        float4 bb = *(const float4*)(&sb[o]);
        float4 w = *(const float4*)(&sw[o]);
        acc += fmaxf(a.x + b.x + bb.x, 0.f) * w.x;
        acc += fmaxf(a.y + b.y + bb.y, 0.f) * w.y;
        acc += fmaxf(a.z + b.z + bb.z, 0.f) * w.z;
        acc += fmaxf(a.w + b.w + bb.w, 0.f) * w.w;
    }
    out[p] = acc;
}

extern "C" void kernel_launch(void* const* d_in, const int* in_sizes, int n_in,
                              void* d_out, int out_size, void* d_ws, size_t ws_size,
                              hipStream_t stream) {
    const float* x    = (const float*)d_in[0];
    const int*   ei   = (const int*)d_in[1];
    const int*   eli  = (const int*)d_in[2];
    const float* w1l  = (const float*)d_in[3];
    const float* b1l  = (const float*)d_in[4];
    const float* w1r  = (const float*)d_in[5];
    const float* w2l  = (const float*)d_in[6];
    const float* b2l  = (const float*)d_in[7];
    const float* w2r  = (const float*)d_in[8];
    const float* w3l  = (const float*)d_in[9];
    const float* b3l  = (const float*)d_in[10];
    const float* w3r  = (const float*)d_in[11];
    const float* bn1g = (const float*)d_in[12];
    const float* bn1b = (const float*)d_in[13];
    const float* bn1m = (const float*)d_in[14];
    const float* bn1v = (const float*)d_in[15];
    const float* bn2g = (const float*)d_in[16];
    const float* bn2b = (const float*)d_in[17];
    const float* bn2m = (const float*)d_in[18];
    const float* bn2v = (const float*)d_in[19];
    const float* dw1  = (const float*)d_in[20];
    const float* db1  = (const float*)d_in[21];
    const float* dw2  = (const float*)d_in[22];
    const float* db2  = (const float*)d_in[23];
    float* out = (float*)d_out;

    const int N = in_sizes[0] / 256;
    const int E = in_sizes[1] / 2;
    const int L = in_sizes[2] / 2;
    const int* src = ei;
    const int* dst = ei + E;
    const int ntiles = (N + 1023) >> 10;
    const int nblk = (N + 127) / 128;
    const int Npad = nblk * 128;

    char* wsb = (char*)d_ws;
    size_t off = 0;
    auto carve = [&](size_t bytes) -> void* {
        void* p = wsb + off;
        off += (bytes + 255) & ~(size_t)255;
        return p;
    };
    int* ptr        = (int*)carve((size_t)(N + 1) * 4);
    int* cnt        = (int*)carve((size_t)N * 4);
    int* rank       = (int*)carve((size_t)E * 4);
    int* tilesum    = (int*)carve((size_t)ntiles * 4);
    int* edges      = (int*)carve((size_t)E * 4);
    ushort* WS1     = (ushort*)carve((size_t)256 * 768 * 2);
    ushort* WS2     = (ushort*)carve((size_t)256 * 384 * 2);
    ushort* WS3     = (ushort*)carve((size_t)256 * 384 * 2);
    ushort* WS4     = (ushort*)carve((size_t)256 * 384 * 2);
    ushort* tl_h    = (ushort*)carve((size_t)N * 128 * 2);   // neighbor-transform (fp16)
    float* tr_c     = (float*)carve((size_t)N * 128 * 4);    // root-transform (f32) / dec-v (fp16)
    ushort* A3      = (ushort*)carve((size_t)Npad * 512 * 2); // layer-1 [hi|lo]
    ushort* h3      = A3;                                     // reuse: [Npad][256]

    // ---- CSR build (count+rank, scan, atomic-free scatter) ----
    hipMemsetAsync(cnt, 0, (size_t)N * 4, stream);
    count_kernel<<<(E + 255) / 256, 256, 0, stream>>>(dst, cnt, rank, E);
    scanA_kernel<<<ntiles, 1024, 0, stream>>>(cnt, ptr, tilesum, N);
    scanB_kernel<<<1, 64, 0, stream>>>(tilesum, ptr, ntiles, N);
    scanC_kernel<<<(N + 255) / 256, 256, 0, stream>>>(ptr, tilesum, N);
    scatter_kernel<<<(E + 255) / 256, 256, 0, stream>>>(src, dst, ptr, rank, edges, E);

    // ---- conversions ----
    convx_kernel<<<(N * 64 + 255) / 256, 256, 0, stream>>>(x, A3, N * 64);
    wprep_all_kernel<<<dim3(256, 4), 256, 0, stream>>>(w1l, w1r, w2l, w2r, w3l, w3r,
                                                       dw1, WS1, WS2, WS3, WS4);

    // ---- layer 1 ----
    mm_kernel<512, 0><<<nblk, 256, 0, stream>>>(A3, WS1, tl_h, tr_c, N);
    agg_kernel<<<(N + 3) / 4, 256, 0, stream>>>(tl_h, tr_c, ptr, edges, b1l,
                                                bn1g, bn1b, bn1m, bn1v, 1, h3, N);
    // ---- layer 2 ----
    mm_kernel<256, 0><<<nblk, 256, 0, stream>>>(h3, WS2, tl_h, tr_c, N);
    agg_kernel<<<(N + 3) / 4, 256, 0, stream>>>(tl_h, tr_c, ptr, edges, b2l,
                                                bn2g, bn2b, bn2m, bn2v, 1, h3, N);
    // ---- layer 3 (no BN) ----
    mm_kernel<256, 0><<<nblk, 256, 0, stream>>>(h3, WS3, tl_h, tr_c, N);
    agg_kernel<<<(N + 3) / 4, 256, 0, stream>>>(tl_h, tr_c, ptr, edges, b3l,
                                                bn1g, bn1b, bn1m, bn1v, 0, h3, N);
    // ---- decoder transforms u|v (both fp16), then pair decode ----
    mm_kernel<256, 1><<<nblk, 256, 0, stream>>>(h3, WS4, tl_h, tr_c, N);
    decode_kernel<<<(L + 255) / 256, 256, 0, stream>>>(tl_h, (const ushort*)tr_c, eli,
                                                       db1, dw2, db2, out, L);
}

// Round 12
// 359.996 us; speedup vs baseline: 1.2132x; 1.0180x over previous
//
#include <hip/hip_runtime.h>
#include <hip/hip_fp16.h>

// ---------------------------------------------------------------------------
// GraphSAGE (3x SAGEConv mean-agg + BN/ReLU) + link decoder.
// R12 changes vs R11:
//  - prep_kernel: convx + count/rank + wprep fused into ONE launch (block-range
//    split; independent work overlaps instead of serializing ~34us -> ~18us).
//  - agg: edge-index software prefetch (next iter's 8 indices load during
//    current iter's gathers) + dual-gather tail (2 independent chains).
//  - everything else identical to R11.
// ---------------------------------------------------------------------------

typedef unsigned int uint;
using s16x8 = __attribute__((ext_vector_type(8))) short;
using f32x4 = __attribute__((ext_vector_type(4))) float;

__device__ inline void bsplit(float v, ushort& hi, ushort& lo) {
    // round-to-nearest-even bf16 split: v ~= hi + lo to ~2^-17 rel
    uint u = __float_as_uint(v);
    uint hb = (u + 0x7FFFu + ((u >> 16) & 1u)) >> 16;
    hi = (ushort)hb;
    float r = v - __uint_as_float(hb << 16);
    uint u2 = __float_as_uint(r);
    lo = (ushort)((u2 + 0x7FFFu + ((u2 >> 16) & 1u)) >> 16);
}

__device__ inline ushort f2h(float v) { return __half_as_ushort(__float2half(v)); }

__device__ inline float4 h4f(uint2 r) {
    float2 fa = __half22float2(*(const __half2*)&r.x);
    float2 fb = __half22float2(*(const __half2*)&r.y);
    return make_float4(fa.x, fa.y, fb.x, fb.y);
}

// swizzle a ushort index within its 64-ushort K-slice: chunk ^= (row&7)
__device__ inline uint swz(uint i, uint r) {
    return (i & ~63u) | ((i ^ (r << 3)) & 56u) | (i & 7u);
}

// async global->LDS, 16 bytes per lane
__device__ inline void gload16(const void* g, void* l) {
    __builtin_amdgcn_global_load_lds(
        (const __attribute__((address_space(1))) unsigned int*)g,
        (__attribute__((address_space(3))) unsigned int*)l, 16, 0, 0);
}

// ---------------- fused prologue: convx | count+rank | wprep ----------------
__global__ __launch_bounds__(256) void prep_kernel(
    const float* __restrict__ x, ushort* __restrict__ A3, int totalconv, int nconv,
    const int* __restrict__ dst, int* __restrict__ cnt, int* __restrict__ rank,
    int E, int ncount,
    const float* __restrict__ w1l, const float* __restrict__ w1r,
    const float* __restrict__ w2l, const float* __restrict__ w2r,
    const float* __restrict__ w3l, const float* __restrict__ w3r,
    const float* __restrict__ dw1,
    ushort* __restrict__ WS1, ushort* __restrict__ WS2,
    ushort* __restrict__ WS3, ushort* __restrict__ WS4)
{
    const int bid = blockIdx.x;
    if (bid < nconv) {
        // ---- convx: x[N][256] -> A3[N][512] = [hi|lo], pre-swizzled
        int e = bid * 256 + threadIdx.x;
        if (e >= totalconv) return;
        uint row = e >> 6;
        uint k4 = (e & 63) << 2;
        float4 v = *(const float4*)(x + (size_t)row * 256 + k4);
        ushort4 hi, lo;
        bsplit(v.x, hi.x, lo.x); bsplit(v.y, hi.y, lo.y);
        bsplit(v.z, hi.z, lo.z); bsplit(v.w, hi.w, lo.w);
        ushort* d = A3 + (size_t)row * 512;
        *(ushort4*)(d + swz(k4, row))       = hi;
        *(ushort4*)(d + swz(k4 + 256, row)) = lo;
    } else if (bid < nconv + ncount) {
        // ---- count + rank
        int i = (bid - nconv) * 256 + threadIdx.x;
        if (i < E) rank[i] = atomicAdd(&cnt[dst[i]], 1);
    } else {
        // ---- wprep: 1024 blocks = 4 layers x 256 output rows
        int w = bid - nconv - ncount;
        uint n = w & 255;
        int which = w >> 8;
        uint k = threadIdx.x;
        const float *wa, *wb;
        uint K, lda, aoff, boff;
        ushort* WS;
        switch (which) {
            case 0:  wa = w1l; wb = w1r; K = 256; lda = 256; aoff = 0; boff = 0;   WS = WS1; break;
            case 1:  wa = w2l; wb = w2r; K = 128; lda = 128; aoff = 0; boff = 0;   WS = WS2; break;
            case 2:  wa = w3l; wb = w3r; K = 128; lda = 128; aoff = 0; boff = 0;   WS = WS3; break;
            default: wa = dw1; wb = dw1; K = 128; lda = 256; aoff = 0; boff = 128; WS = WS4; break;
        }
        if (k >= K) return;
        const float* srcr = (n < 128) ? (wa + (size_t)n * lda + aoff)
                                      : (wb + (size_t)(n - 128) * lda + boff);
        ushort hi, lo;
        bsplit(srcr[k], hi, lo);
        ushort* d = WS + (size_t)n * 3 * K;
        d[swz(k, n)]         = hi;
        d[swz(K + k, n)]     = lo;
        d[swz(2 * K + k, n)] = hi;
    }
}

// ---------------- scans + scatter ----------------
__global__ void scanA_kernel(const int* __restrict__ cnt, int* __restrict__ ptr,
                             int* __restrict__ tilesum, int n) {
    __shared__ int sd[1024];
    int t = threadIdx.x;
    int i = blockIdx.x * 1024 + t;
    int v = (i < n) ? cnt[i] : 0;
    sd[t] = v;
    __syncthreads();
    #pragma unroll
    for (int off = 1; off < 1024; off <<= 1) {
        int add = (t >= off) ? sd[t - off] : 0;
        __syncthreads();
        sd[t] += add;
        __syncthreads();
    }
    if (i < n) ptr[i] = sd[t] - v;              // local exclusive
    if (t == 1023) tilesum[blockIdx.x] = sd[t]; // tile total
}

__global__ void scanB_kernel(int* __restrict__ tilesum, int* __restrict__ ptr,
                             int ntiles, int n) {
    if (threadIdx.x == 0 && blockIdx.x == 0) {
        int running = 0;
        for (int b = 0; b < ntiles; ++b) {
            int t = tilesum[b];
            tilesum[b] = running;
            running += t;
        }
        ptr[n] = running;
    }
}

__global__ void scanC_kernel(int* __restrict__ ptr, const int* __restrict__ tilesum, int n) {
    int i = blockIdx.x * blockDim.x + threadIdx.x;
    if (i < n) ptr[i] += tilesum[i >> 10];
}

// atomic-free scatter using precomputed ranks
__global__ void scatter_kernel(const int* __restrict__ src, const int* __restrict__ dst,
                               const int* __restrict__ ptr, const int* __restrict__ rank,
                               int* __restrict__ edges, int E) {
    int i = blockIdx.x * blockDim.x + threadIdx.x;
    if (i < E) edges[ptr[dst[i]] + rank[i]] = src[i];
}

// ---------------- MFMA GEMM ----------------
// Block = 128 rows x 256 cols. 4 waves, each 64x128.
// A[M][KP] = [hi|lo] pre-swizzled; W[256][KP*3/2] = [Wh|Wlo|Wh] pre-swizzled.
// Staging = global_load_lds 16B into LINEAR LDS; ds_read applies the XOR.
// Cl (cols 0..127) written fp16; Cr written fp16 iff CRF16 else f32.
template <int KP, int CRF16>
__global__ __launch_bounds__(256, 2) void mm_kernel(const ushort* __restrict__ A,
                                                    const ushort* __restrict__ WS,
                                                    ushort* __restrict__ Cl,
                                                    void* __restrict__ Cr_, int M) {
    constexpr int KS  = (KP / 64) + (KP / 128);   // 12 (KP=512) or 6 (KP=256)
    constexpr int WKP = KP + KP / 2;
    __shared__ ushort At[128 * 64];
    __shared__ ushort Bt[256 * 64];
    const int t = threadIdx.x;
    const int lane = t & 63;
    const int wave = t >> 6;
    const int wm = wave >> 1, wn = wave & 1;      // 2 row-halves x 2 col-halves
    const int row0 = blockIdx.x * 128;
    const int l15 = lane & 15;
    const int l4 = lane >> 4;
    const int l8 = lane >> 3;                     // staging row within 8-row group
    const int c8 = lane & 7;                      // staging chunk within row

    f32x4 acc[4][8] = {};

    for (int s = 0; s < KS; ++s) {
        const int as = (s < KP / 128) ? s : s - (KP / 128);
        #pragma unroll
        for (int j = 0; j < 4; ++j) {
            int jj = wave + j * 4;                // A group 0..15
            int r = jj * 8 + l8;
            gload16(A + (size_t)(row0 + r) * KP + as * 64 + c8 * 8,
                    (char*)At + jj * 1024 + lane * 16);
        }
        #pragma unroll
        for (int j = 0; j < 8; ++j) {
            int jj = wave + j * 4;                // B group 0..31
            int r = jj * 8 + l8;
            gload16(WS + (size_t)r * WKP + s * 64 + c8 * 8,
                    (char*)Bt + jj * 1024 + lane * 16);
        }
        __syncthreads();
        #pragma unroll
        for (int kk = 0; kk < 64; kk += 32) {
            s16x8 af[4], bf[8];
            #pragma unroll
            for (int mi = 0; mi < 4; ++mi) {
                int r = wm * 64 + mi * 16 + l15;
                int off = (kk + l4 * 8) ^ ((r & 7) * 8);
                af[mi] = *(const s16x8*)&At[r * 64 + off];
            }
            #pragma unroll
            for (int ni = 0; ni < 8; ++ni) {
                int r = wn * 128 + ni * 16 + l15;
                int off = (kk + l4 * 8) ^ ((r & 7) * 8);
                bf[ni] = *(const s16x8*)&Bt[r * 64 + off];
            }
            #pragma unroll
            for (int mi = 0; mi < 4; ++mi)
                #pragma unroll
                for (int ni = 0; ni < 8; ++ni)
                    acc[mi][ni] = __builtin_amdgcn_mfma_f32_16x16x32_bf16(
                        af[mi], bf[ni], acc[mi][ni], 0, 0, 0);
        }
        __syncthreads();
    }
    // ---- epilogue: row = (lane>>4)*4+j, col = lane&15 within 16x16
    #pragma unroll
    for (int mi = 0; mi < 4; ++mi) {
        int rbase = row0 + wm * 64 + mi * 16 + l4 * 4;
        #pragma unroll
        for (int ni = 0; ni < 8; ++ni) {
            int col = ni * 16 + l15;
            #pragma unroll
            for (int j = 0; j < 4; ++j) {
                int r = rbase + j;
                if (r < M) {
                    if (wn == 0) {
                        Cl[(size_t)r * 128 + col] = f2h(acc[mi][ni][j]);
                    } else if (CRF16) {
                        ((ushort*)Cr_)[(size_t)r * 128 + col] = f2h(acc[mi][ni][j]);
                    } else {
                        ((float*)Cr_)[(size_t)r * 128 + col] = acc[mi][ni][j];
                    }
                }
            }
        }
    }
}

// ---------------- aggregation ----------------
// One node per wave; lanes 0-31 even edge slots, 32-63 odd; shfl_xor combine.
// Edge-index prefetch: next iter's indices load during current gathers.
// tl is fp16 (256B/row gathers); root tr is f32 (streamed).
__global__ __launch_bounds__(256, 4) void agg_kernel(
    const ushort* __restrict__ tl, const float* __restrict__ tr,
    const int* __restrict__ ptr, const int* __restrict__ edges,
    const float* __restrict__ bl,
    const float* __restrict__ bng, const float* __restrict__ bnb,
    const float* __restrict__ bnm, const float* __restrict__ bnv,
    int do_bn, ushort* __restrict__ h3, int n) {
    const int wave = threadIdx.x >> 6;
    const int lane = threadIdx.x & 63;
    const uint node = blockIdx.x * 4 + wave;
    if (node >= (uint)n) return;
    const int half = lane >> 5;
    const uint q4 = (lane & 31) << 2;             // 4 feats per lane
    const int p0 = ptr[node], p1 = ptr[node + 1];
    float4 a0 = make_float4(0.f, 0.f, 0.f, 0.f), a1 = a0, a2 = a0, a3 = a0;
    float4 a4 = a0, a5 = a0, a6 = a0, a7 = a0;
    int e = p0 + half;
    int i0 = 0, i1 = 0, i2 = 0, i3 = 0, i4 = 0, i5 = 0, i6 = 0, i7 = 0;
    bool have = (e + 14 < p1);
    if (have) {
        i0 = edges[e];      i1 = edges[e + 2];  i2 = edges[e + 4];  i3 = edges[e + 6];
        i4 = edges[e + 8];  i5 = edges[e + 10]; i6 = edges[e + 12]; i7 = edges[e + 14];
    }
    while (have) {
        int c0 = i0, c1 = i1, c2 = i2, c3 = i3, c4 = i4, c5 = i5, c6 = i6, c7 = i7;
        e += 16;
        have = (e + 14 < p1);
        if (have) {                               // prefetch next iter's indices
            i0 = edges[e];      i1 = edges[e + 2];  i2 = edges[e + 4];  i3 = edges[e + 6];
            i4 = edges[e + 8];  i5 = edges[e + 10]; i6 = edges[e + 12]; i7 = edges[e + 14];
        }
        uint2 r0 = *(const uint2*)(tl + (size_t)c0 * 128 + q4);
        uint2 r1 = *(const uint2*)(tl + (size_t)c1 * 128 + q4);
        uint2 r2 = *(const uint2*)(tl + (size_t)c2 * 128 + q4);
        uint2 r3 = *(const uint2*)(tl + (size_t)c3 * 128 + q4);
        uint2 r4 = *(const uint2*)(tl + (size_t)c4 * 128 + q4);
        uint2 r5 = *(const uint2*)(tl + (size_t)c5 * 128 + q4);
        uint2 r6 = *(const uint2*)(tl + (size_t)c6 * 128 + q4);
        uint2 r7 = *(const uint2*)(tl + (size_t)c7 * 128 + q4);
        float4 v0 = h4f(r0), v1 = h4f(r1), v2 = h4f(r2), v3 = h4f(r3);
        float4 v4 = h4f(r4), v5 = h4f(r5), v6 = h4f(r6), v7 = h4f(r7);
        a0.x += v0.x; a0.y += v0.y; a0.z += v0.z; a0.w += v0.w;
        a1.x += v1.x; a1.y += v1.y; a1.z += v1.z; a1.w += v1.w;
        a2.x += v2.x; a2.y += v2.y; a2.z += v2.z; a2.w += v2.w;
        a3.x += v3.x; a3.y += v3.y; a3.z += v3.z; a3.w += v3.w;
        a4.x += v4.x; a4.y += v4.y; a4.z += v4.z; a4.w += v4.w;
        a5.x += v5.x; a5.y += v5.y; a5.z += v5.z; a5.w += v5.w;
        a6.x += v6.x; a6.y += v6.y; a6.z += v6.z; a6.w += v6.w;
        a7.x += v7.x; a7.y += v7.y; a7.z += v7.z; a7.w += v7.w;
    }
    // tail: 2 independent gathers per iter
    for (; e + 2 < p1; e += 4) {
        int c0 = edges[e], c1 = edges[e + 2];
        float4 v0 = h4f(*(const uint2*)(tl + (size_t)c0 * 128 + q4));
        float4 v1 = h4f(*(const uint2*)(tl + (size_t)c1 * 128 + q4));
        a0.x += v0.x; a0.y += v0.y; a0.z += v0.z; a0.w += v0.w;
        a1.x += v1.x; a1.y += v1.y; a1.z += v1.z; a1.w += v1.w;
    }
    if (e < p1) {
        int c0 = edges[e];
        float4 v0 = h4f(*(const uint2*)(tl + (size_t)c0 * 128 + q4));
        a2.x += v0.x; a2.y += v0.y; a2.z += v0.z; a2.w += v0.w;
    }
    float4 s;
    s.x = ((a0.x + a1.x) + (a2.x + a3.x)) + ((a4.x + a5.x) + (a6.x + a7.x));
    s.y = ((a0.y + a1.y) + (a2.y + a3.y)) + ((a4.y + a5.y) + (a6.y + a7.y));
    s.z = ((a0.z + a1.z) + (a2.z + a3.z)) + ((a4.z + a5.z) + (a6.z + a7.z));
    s.w = ((a0.w + a1.w) + (a2.w + a3.w)) + ((a4.w + a5.w) + (a6.w + a7.w));
    // combine even/odd halves (lane <-> lane^32)
    s.x += __shfl_xor(s.x, 32);
    s.y += __shfl_xor(s.y, 32);
    s.z += __shfl_xor(s.z, 32);
    s.w += __shfl_xor(s.w, 32);
    if (half == 0) {
        float inv = 1.f / fmaxf((float)(p1 - p0), 1.f);
        float4 r = *(const float4*)(tr + (size_t)node * 128 + q4);
        float4 b = *(const float4*)(bl + q4);
        float4 val;
        val.x = fmaf(s.x, inv, b.x) + r.x;
        val.y = fmaf(s.y, inv, b.y) + r.y;
        val.z = fmaf(s.z, inv, b.z) + r.z;
        val.w = fmaf(s.w, inv, b.w) + r.w;
        if (do_bn) {
            float4 g = *(const float4*)(bng + q4);
            float4 be = *(const float4*)(bnb + q4);
            float4 m = *(const float4*)(bnm + q4);
            float4 vv = *(const float4*)(bnv + q4);
            val.x = fmaxf(fmaf(val.x - m.x, g.x * rsqrtf(vv.x + 1e-5f), be.x), 0.f);
            val.y = fmaxf(fmaf(val.y - m.y, g.y * rsqrtf(vv.y + 1e-5f), be.y), 0.f);
            val.z = fmaxf(fmaf(val.z - m.z, g.z * rsqrtf(vv.z + 1e-5f), be.z), 0.f);
            val.w = fmaxf(fmaf(val.w - m.w, g.w * rsqrtf(vv.w + 1e-5f), be.w), 0.f);
        }
        ushort4 hi, lo;
        bsplit(val.x, hi.x, lo.x); bsplit(val.y, hi.y, lo.y);
        bsplit(val.z, hi.z, lo.z); bsplit(val.w, hi.w, lo.w);
        ushort* d = h3 + (size_t)node * 256;
        *(ushort4*)(d + swz(q4, node))       = hi;
        *(ushort4*)(d + swz(q4 + 128, node)) = lo;
    }
}

// ---------------- decoder: relu(u[s] + v[d] + b) . w2 + b2 (u,v fp16) -------
__global__ __launch_bounds__(256) void decode_kernel(
    const ushort* __restrict__ u, const ushort* __restrict__ v,
    const int* __restrict__ eli, const float* __restrict__ db1,
    const float* __restrict__ dw2, const float* __restrict__ db2,
    float* __restrict__ out, int L) {
    __shared__ float sb[128], sw[128];
    if (threadIdx.x < 128) {
        sb[threadIdx.x] = db1[threadIdx.x];
        sw[threadIdx.x] = dw2[threadIdx.x];
    }
    __syncthreads();
    int p = blockIdx.x * 256 + threadIdx.x;
    if (p >= L) return;
    int s = eli[p], d = eli[L + p];
    const ushort* up = u + (size_t)s * 128;
    const ushort* vp = v + (size_t)d * 128;
    float acc = db2[0];
    #pragma unroll 8
    for (int o = 0; o < 128; o += 4) {
        float4 a = h4f(*(const uint2*)(up + o));
        float4 b = h4f(*(const uint2*)(vp + o));
        float4 bb = *(const float4*)(&sb[o]);
        float4 w = *(const float4*)(&sw[o]);
        acc += fmaxf(a.x + b.x + bb.x, 0.f) * w.x;
        acc += fmaxf(a.y + b.y + bb.y, 0.f) * w.y;
        acc += fmaxf(a.z + b.z + bb.z, 0.f) * w.z;
        acc += fmaxf(a.w + b.w + bb.w, 0.f) * w.w;
    }
    out[p] = acc;
}

extern "C" void kernel_launch(void* const* d_in, const int* in_sizes, int n_in,
                              void* d_out, int out_size, void* d_ws, size_t ws_size,
                              hipStream_t stream) {
    const float* x    = (const float*)d_in[0];
    const int*   ei   = (const int*)d_in[1];
    const int*   eli  = (const int*)d_in[2];
    const float* w1l  = (const float*)d_in[3];
    const float* b1l  = (const float*)d_in[4];
    const float* w1r  = (const float*)d_in[5];
    const float* w2l  = (const float*)d_in[6];
    const float* b2l  = (const float*)d_in[7];
    const float* w2r  = (const float*)d_in[8];
    const float* w3l  = (const float*)d_in[9];
    const float* b3l  = (const float*)d_in[10];
    const float* w3r  = (const float*)d_in[11];
    const float* bn1g = (const float*)d_in[12];
    const float* bn1b = (const float*)d_in[13];
    const float* bn1m = (const float*)d_in[14];
    const float* bn1v = (const float*)d_in[15];
    const float* bn2g = (const float*)d_in[16];
    const float* bn2b = (const float*)d_in[17];
    const float* bn2m = (const float*)d_in[18];
    const float* bn2v = (const float*)d_in[19];
    const float* dw1  = (const float*)d_in[20];
    const float* db1  = (const float*)d_in[21];
    const float* dw2  = (const float*)d_in[22];
    const float* db2  = (const float*)d_in[23];
    float* out = (float*)d_out;

    const int N = in_sizes[0] / 256;
    const int E = in_sizes[1] / 2;
    const int L = in_sizes[2] / 2;
    const int* src = ei;
    const int* dst = ei + E;
    const int ntiles = (N + 1023) >> 10;
    const int nblk = (N + 127) / 128;
    const int Npad = nblk * 128;
    const int nconv = (N * 64 + 255) / 256;
    const int ncount = (E + 255) / 256;

    char* wsb = (char*)d_ws;
    size_t off = 0;
    auto carve = [&](size_t bytes) -> void* {
        void* p = wsb + off;
        off += (bytes + 255) & ~(size_t)255;
        return p;
    };
    int* ptr        = (int*)carve((size_t)(N + 1) * 4);
    int* cnt        = (int*)carve((size_t)N * 4);
    int* rank       = (int*)carve((size_t)E * 4);
    int* tilesum    = (int*)carve((size_t)ntiles * 4);
    int* edges      = (int*)carve((size_t)E * 4);
    ushort* WS1     = (ushort*)carve((size_t)256 * 768 * 2);
    ushort* WS2     = (ushort*)carve((size_t)256 * 384 * 2);
    ushort* WS3     = (ushort*)carve((size_t)256 * 384 * 2);
    ushort* WS4     = (ushort*)carve((size_t)256 * 384 * 2);
    ushort* tl_h    = (ushort*)carve((size_t)N * 128 * 2);   // neighbor-transform (fp16)
    float* tr_c     = (float*)carve((size_t)N * 128 * 4);    // root-transform (f32) / dec-v (fp16)
    ushort* A3      = (ushort*)carve((size_t)Npad * 512 * 2); // layer-1 [hi|lo]
    ushort* h3      = A3;                                     // reuse: [Npad][256]

    // ---- fused prologue (convx | count+rank | wprep), then scans + scatter
    hipMemsetAsync(cnt, 0, (size_t)N * 4, stream);
    prep_kernel<<<nconv + ncount + 1024, 256, 0, stream>>>(
        x, A3, N * 64, nconv, dst, cnt, rank, E, ncount,
        w1l, w1r, w2l, w2r, w3l, w3r, dw1, WS1, WS2, WS3, WS4);
    scanA_kernel<<<ntiles, 1024, 0, stream>>>(cnt, ptr, tilesum, N);
    scanB_kernel<<<1, 64, 0, stream>>>(tilesum, ptr, ntiles, N);
    scanC_kernel<<<(N + 255) / 256, 256, 0, stream>>>(ptr, tilesum, N);
    scatter_kernel<<<(E + 255) / 256, 256, 0, stream>>>(src, dst, ptr, rank, edges, E);

    // ---- layer 1 ----
    mm_kernel<512, 0><<<nblk, 256, 0, stream>>>(A3, WS1, tl_h, tr_c, N);
    agg_kernel<<<(N + 3) / 4, 256, 0, stream>>>(tl_h, tr_c, ptr, edges, b1l,
                                                bn1g, bn1b, bn1m, bn1v, 1, h3, N);
    // ---- layer 2 ----
    mm_kernel<256, 0><<<nblk, 256, 0, stream>>>(h3, WS2, tl_h, tr_c, N);
    agg_kernel<<<(N + 3) / 4, 256, 0, stream>>>(tl_h, tr_c, ptr, edges, b2l,
                                                bn2g, bn2b, bn2m, bn2v, 1, h3, N);
    // ---- layer 3 (no BN) ----
    mm_kernel<256, 0><<<nblk, 256, 0, stream>>>(h3, WS3, tl_h, tr_c, N);
    agg_kernel<<<(N + 3) / 4, 256, 0, stream>>>(tl_h, tr_c, ptr, edges, b3l,
                                                bn1g, bn1b, bn1m, bn1v, 0, h3, N);
    // ---- decoder transforms u|v (both fp16), then pair decode ----
    mm_kernel<256, 1><<<nblk, 256, 0, stream>>>(h3, WS4, tl_h, tr_c, N);
    decode_kernel<<<(L + 255) / 256, 256, 0, stream>>>(tl_h, (const ushort*)tr_c, eli,
                                                       db1, dw2, db2, out, L);
}

// Round 13
// 341.486 us; speedup vs baseline: 1.2790x; 1.0542x over previous
//
#include <hip/hip_runtime.h>
#include <hip/hip_fp16.h>

// ---------------------------------------------------------------------------
// GraphSAGE (3x SAGEConv mean-agg + BN/ReLU) + link decoder.
// R13 changes vs R12:
//  - prep roles INTERLEAVED by bid&15 (12 convx : 3 count : 1 wprep) instead
//    of range-based -> the three independent workloads are truly co-resident
//    (R12's range split still serialized through the dispatch queue).
//  - scanB folded into scanC (each block computes the <=48-tile prefix
//    locally; block 0 writes ptr[N]); one fewer serial launch.
//  - agg/mm/scatter/decode unchanged from R12.
// ---------------------------------------------------------------------------

typedef unsigned int uint;
using s16x8 = __attribute__((ext_vector_type(8))) short;
using f32x4 = __attribute__((ext_vector_type(4))) float;

__device__ inline void bsplit(float v, ushort& hi, ushort& lo) {
    // round-to-nearest-even bf16 split: v ~= hi + lo to ~2^-17 rel
    uint u = __float_as_uint(v);
    uint hb = (u + 0x7FFFu + ((u >> 16) & 1u)) >> 16;
    hi = (ushort)hb;
    float r = v - __uint_as_float(hb << 16);
    uint u2 = __float_as_uint(r);
    lo = (ushort)((u2 + 0x7FFFu + ((u2 >> 16) & 1u)) >> 16);
}

__device__ inline ushort f2h(float v) { return __half_as_ushort(__float2half(v)); }

__device__ inline float4 h4f(uint2 r) {
    float2 fa = __half22float2(*(const __half2*)&r.x);
    float2 fb = __half22float2(*(const __half2*)&r.y);
    return make_float4(fa.x, fa.y, fb.x, fb.y);
}

// swizzle a ushort index within its 64-ushort K-slice: chunk ^= (row&7)
__device__ inline uint swz(uint i, uint r) {
    return (i & ~63u) | ((i ^ (r << 3)) & 56u) | (i & 7u);
}

// async global->LDS, 16 bytes per lane
__device__ inline void gload16(const void* g, void* l) {
    __builtin_amdgcn_global_load_lds(
        (const __attribute__((address_space(1))) unsigned int*)g,
        (__attribute__((address_space(3))) unsigned int*)l, 16, 0, 0);
}

// ---------------- fused prologue: interleaved convx | count+rank | wprep ----
__global__ __launch_bounds__(256) void prep_kernel(
    const float* __restrict__ x, ushort* __restrict__ A3, int totalconv, int nconv,
    const int* __restrict__ dst, int* __restrict__ cnt, int* __restrict__ rank,
    int E, int ncount,
    const float* __restrict__ w1l, const float* __restrict__ w1r,
    const float* __restrict__ w2l, const float* __restrict__ w2r,
    const float* __restrict__ w3l, const float* __restrict__ w3r,
    const float* __restrict__ dw1,
    ushort* __restrict__ WS1, ushort* __restrict__ WS2,
    ushort* __restrict__ WS3, ushort* __restrict__ WS4)
{
    const int g = blockIdx.x >> 4;
    const int r16 = blockIdx.x & 15;
    if (r16 < 12) {
        // ---- convx: x[N][256] -> A3[N][512] = [hi|lo], pre-swizzled
        int ci = g * 12 + r16;
        if (ci >= nconv) return;
        int e = ci * 256 + threadIdx.x;
        if (e >= totalconv) return;
        uint row = e >> 6;
        uint k4 = (e & 63) << 2;
        float4 v = *(const float4*)(x + (size_t)row * 256 + k4);
        ushort4 hi, lo;
        bsplit(v.x, hi.x, lo.x); bsplit(v.y, hi.y, lo.y);
        bsplit(v.z, hi.z, lo.z); bsplit(v.w, hi.w, lo.w);
        ushort* d = A3 + (size_t)row * 512;
        *(ushort4*)(d + swz(k4, row))       = hi;
        *(ushort4*)(d + swz(k4 + 256, row)) = lo;
    } else if (r16 < 15) {
        // ---- count + rank
        int qi = g * 3 + (r16 - 12);
        if (qi >= ncount) return;
        int i = qi * 256 + threadIdx.x;
        if (i < E) rank[i] = atomicAdd(&cnt[dst[i]], 1);
    } else {
        // ---- wprep: 1024 logical blocks = 4 layers x 256 output rows
        int w = g;
        if (w >= 1024) return;
        uint n = w & 255;
        int which = w >> 8;
        uint k = threadIdx.x;
        const float *wa, *wb;
        uint K, lda, aoff, boff;
        ushort* WS;
        switch (which) {
            case 0:  wa = w1l; wb = w1r; K = 256; lda = 256; aoff = 0; boff = 0;   WS = WS1; break;
            case 1:  wa = w2l; wb = w2r; K = 128; lda = 128; aoff = 0; boff = 0;   WS = WS2; break;
            case 2:  wa = w3l; wb = w3r; K = 128; lda = 128; aoff = 0; boff = 0;   WS = WS3; break;
            default: wa = dw1; wb = dw1; K = 128; lda = 256; aoff = 0; boff = 128; WS = WS4; break;
        }
        if (k >= K) return;
        const float* srcr = (n < 128) ? (wa + (size_t)n * lda + aoff)
                                      : (wb + (size_t)(n - 128) * lda + boff);
        ushort hi, lo;
        bsplit(srcr[k], hi, lo);
        ushort* d = WS + (size_t)n * 3 * K;
        d[swz(k, n)]         = hi;
        d[swz(K + k, n)]     = lo;
        d[swz(2 * K + k, n)] = hi;
    }
}

// ---------------- scans + scatter ----------------
__global__ void scanA_kernel(const int* __restrict__ cnt, int* __restrict__ ptr,
                             int* __restrict__ tilesum, int n) {
    __shared__ int sd[1024];
    int t = threadIdx.x;
    int i = blockIdx.x * 1024 + t;
    int v = (i < n) ? cnt[i] : 0;
    sd[t] = v;
    __syncthreads();
    #pragma unroll
    for (int off = 1; off < 1024; off <<= 1) {
        int add = (t >= off) ? sd[t - off] : 0;
        __syncthreads();
        sd[t] += add;
        __syncthreads();
    }
    if (i < n) ptr[i] = sd[t] - v;              // local exclusive
    if (t == 1023) tilesum[blockIdx.x] = sd[t]; // tile total
}

// adds tile-prefix (computed locally; <=ntiles uniform loads) + writes ptr[n]
__global__ void scanC_kernel(int* __restrict__ ptr, const int* __restrict__ tilesum,
                             int n, int ntiles) {
    int i = blockIdx.x * 256 + threadIdx.x;
    int t = i >> 10;                            // uniform within a 256-block
    int base = 0;
    for (int b = 0; b < t; ++b) base += tilesum[b];
    if (i < n) ptr[i] += base;
    if (i == 0) {
        int tot = 0;
        for (int b = 0; b < ntiles; ++b) tot += tilesum[b];
        ptr[n] = tot;
    }
}

// atomic-free scatter using precomputed ranks
__global__ void scatter_kernel(const int* __restrict__ src, const int* __restrict__ dst,
                               const int* __restrict__ ptr, const int* __restrict__ rank,
                               int* __restrict__ edges, int E) {
    int i = blockIdx.x * blockDim.x + threadIdx.x;
    if (i < E) edges[ptr[dst[i]] + rank[i]] = src[i];
}

// ---------------- MFMA GEMM ----------------
// Block = 128 rows x 256 cols. 4 waves, each 64x128.
// A[M][KP] = [hi|lo] pre-swizzled; W[256][KP*3/2] = [Wh|Wlo|Wh] pre-swizzled.
// Staging = global_load_lds 16B into LINEAR LDS; ds_read applies the XOR.
// Cl (cols 0..127) written fp16; Cr written fp16 iff CRF16 else f32.
template <int KP, int CRF16>
__global__ __launch_bounds__(256, 2) void mm_kernel(const ushort* __restrict__ A,
                                                    const ushort* __restrict__ WS,
                                                    ushort* __restrict__ Cl,
                                                    void* __restrict__ Cr_, int M) {
    constexpr int KS  = (KP / 64) + (KP / 128);   // 12 (KP=512) or 6 (KP=256)
    constexpr int WKP = KP + KP / 2;
    __shared__ ushort At[128 * 64];
    __shared__ ushort Bt[256 * 64];
    const int t = threadIdx.x;
    const int lane = t & 63;
    const int wave = t >> 6;
    const int wm = wave >> 1, wn = wave & 1;      // 2 row-halves x 2 col-halves
    const int row0 = blockIdx.x * 128;
    const int l15 = lane & 15;
    const int l4 = lane >> 4;
    const int l8 = lane >> 3;                     // staging row within 8-row group
    const int c8 = lane & 7;                      // staging chunk within row

    f32x4 acc[4][8] = {};

    for (int s = 0; s < KS; ++s) {
        const int as = (s < KP / 128) ? s : s - (KP / 128);
        #pragma unroll
        for (int j = 0; j < 4; ++j) {
            int jj = wave + j * 4;                // A group 0..15
            int r = jj * 8 + l8;
            gload16(A + (size_t)(row0 + r) * KP + as * 64 + c8 * 8,
                    (char*)At + jj * 1024 + lane * 16);
        }
        #pragma unroll
        for (int j = 0; j < 8; ++j) {
            int jj = wave + j * 4;                // B group 0..31
            int r = jj * 8 + l8;
            gload16(WS + (size_t)r * WKP + s * 64 + c8 * 8,
                    (char*)Bt + jj * 1024 + lane * 16);
        }
        __syncthreads();
        #pragma unroll
        for (int kk = 0; kk < 64; kk += 32) {
            s16x8 af[4], bf[8];
            #pragma unroll
            for (int mi = 0; mi < 4; ++mi) {
                int r = wm * 64 + mi * 16 + l15;
                int off = (kk + l4 * 8) ^ ((r & 7) * 8);
                af[mi] = *(const s16x8*)&At[r * 64 + off];
            }
            #pragma unroll
            for (int ni = 0; ni < 8; ++ni) {
                int r = wn * 128 + ni * 16 + l15;
                int off = (kk + l4 * 8) ^ ((r & 7) * 8);
                bf[ni] = *(const s16x8*)&Bt[r * 64 + off];
            }
            #pragma unroll
            for (int mi = 0; mi < 4; ++mi)
                #pragma unroll
                for (int ni = 0; ni < 8; ++ni)
                    acc[mi][ni] = __builtin_amdgcn_mfma_f32_16x16x32_bf16(
                        af[mi], bf[ni], acc[mi][ni], 0, 0, 0);
        }
        __syncthreads();
    }
    // ---- epilogue: row = (lane>>4)*4+j, col = lane&15 within 16x16
    #pragma unroll
    for (int mi = 0; mi < 4; ++mi) {
        int rbase = row0 + wm * 64 + mi * 16 + l4 * 4;
        #pragma unroll
        for (int ni = 0; ni < 8; ++ni) {
            int col = ni * 16 + l15;
            #pragma unroll
            for (int j = 0; j < 4; ++j) {
                int r = rbase + j;
                if (r < M) {
                    if (wn == 0) {
                        Cl[(size_t)r * 128 + col] = f2h(acc[mi][ni][j]);
                    } else if (CRF16) {
                        ((ushort*)Cr_)[(size_t)r * 128 + col] = f2h(acc[mi][ni][j]);
                    } else {
                        ((float*)Cr_)[(size_t)r * 128 + col] = acc[mi][ni][j];
                    }
                }
            }
        }
    }
}

// ---------------- aggregation ----------------
// One node per wave; lanes 0-31 even edge slots, 32-63 odd; shfl_xor combine.
// Edge-index prefetch: next iter's indices load during current gathers.
// tl is fp16 (256B/row gathers); root tr is f32 (streamed).
__global__ __launch_bounds__(256, 4) void agg_kernel(
    const ushort* __restrict__ tl, const float* __restrict__ tr,
    const int* __restrict__ ptr, const int* __restrict__ edges,
    const float* __restrict__ bl,
    const float* __restrict__ bng, const float* __restrict__ bnb,
    const float* __restrict__ bnm, const float* __restrict__ bnv,
    int do_bn, ushort* __restrict__ h3, int n) {
    const int wave = threadIdx.x >> 6;
    const int lane = threadIdx.x & 63;
    const uint node = blockIdx.x * 4 + wave;
    if (node >= (uint)n) return;
    const int half = lane >> 5;
    const uint q4 = (lane & 31) << 2;             // 4 feats per lane
    const int p0 = ptr[node], p1 = ptr[node + 1];
    float4 a0 = make_float4(0.f, 0.f, 0.f, 0.f), a1 = a0, a2 = a0, a3 = a0;
    float4 a4 = a0, a5 = a0, a6 = a0, a7 = a0;
    int e = p0 + half;
    int i0 = 0, i1 = 0, i2 = 0, i3 = 0, i4 = 0, i5 = 0, i6 = 0, i7 = 0;
    bool have = (e + 14 < p1);
    if (have) {
        i0 = edges[e];      i1 = edges[e + 2];  i2 = edges[e + 4];  i3 = edges[e + 6];
        i4 = edges[e + 8];  i5 = edges[e + 10]; i6 = edges[e + 12]; i7 = edges[e + 14];
    }
    while (have) {
        int c0 = i0, c1 = i1, c2 = i2, c3 = i3, c4 = i4, c5 = i5, c6 = i6, c7 = i7;
        e += 16;
        have = (e + 14 < p1);
        if (have) {                               // prefetch next iter's indices
            i0 = edges[e];      i1 = edges[e + 2];  i2 = edges[e + 4];  i3 = edges[e + 6];
            i4 = edges[e + 8];  i5 = edges[e + 10]; i6 = edges[e + 12]; i7 = edges[e + 14];
        }
        uint2 r0 = *(const uint2*)(tl + (size_t)c0 * 128 + q4);
        uint2 r1 = *(const uint2*)(tl + (size_t)c1 * 128 + q4);
        uint2 r2 = *(const uint2*)(tl + (size_t)c2 * 128 + q4);
        uint2 r3 = *(const uint2*)(tl + (size_t)c3 * 128 + q4);
        uint2 r4 = *(const uint2*)(tl + (size_t)c4 * 128 + q4);
        uint2 r5 = *(const uint2*)(tl + (size_t)c5 * 128 + q4);
        uint2 r6 = *(const uint2*)(tl + (size_t)c6 * 128 + q4);
        uint2 r7 = *(const uint2*)(tl + (size_t)c7 * 128 + q4);
        float4 v0 = h4f(r0), v1 = h4f(r1), v2 = h4f(r2), v3 = h4f(r3);
        float4 v4 = h4f(r4), v5 = h4f(r5), v6 = h4f(r6), v7 = h4f(r7);
        a0.x += v0.x; a0.y += v0.y; a0.z += v0.z; a0.w += v0.w;
        a1.x += v1.x; a1.y += v1.y; a1.z += v1.z; a1.w += v1.w;
        a2.x += v2.x; a2.y += v2.y; a2.z += v2.z; a2.w += v2.w;
        a3.x += v3.x; a3.y += v3.y; a3.z += v3.z; a3.w += v3.w;
        a4.x += v4.x; a4.y += v4.y; a4.z += v4.z; a4.w += v4.w;
        a5.x += v5.x; a5.y += v5.y; a5.z += v5.z; a5.w += v5.w;
        a6.x += v6.x; a6.y += v6.y; a6.z += v6.z; a6.w += v6.w;
        a7.x += v7.x; a7.y += v7.y; a7.z += v7.z; a7.w += v7.w;
    }
    // tail: 2 independent gathers per iter
    for (; e + 2 < p1; e += 4) {
        int c0 = edges[e], c1 = edges[e + 2];
        float4 v0 = h4f(*(const uint2*)(tl + (size_t)c0 * 128 + q4));
        float4 v1 = h4f(*(const uint2*)(tl + (size_t)c1 * 128 + q4));
        a0.x += v0.x; a0.y += v0.y; a0.z += v0.z; a0.w += v0.w;
        a1.x += v1.x; a1.y += v1.y; a1.z += v1.z; a1.w += v1.w;
    }
    if (e < p1) {
        int c0 = edges[e];
        float4 v0 = h4f(*(const uint2*)(tl + (size_t)c0 * 128 + q4));
        a2.x += v0.x; a2.y += v0.y; a2.z += v0.z; a2.w += v0.w;
    }
    float4 s;
    s.x = ((a0.x + a1.x) + (a2.x + a3.x)) + ((a4.x + a5.x) + (a6.x + a7.x));
    s.y = ((a0.y + a1.y) + (a2.y + a3.y)) + ((a4.y + a5.y) + (a6.y + a7.y));
    s.z = ((a0.z + a1.z) + (a2.z + a3.z)) + ((a4.z + a5.z) + (a6.z + a7.z));
    s.w = ((a0.w + a1.w) + (a2.w + a3.w)) + ((a4.w + a5.w) + (a6.w + a7.w));
    // combine even/odd halves (lane <-> lane^32)
    s.x += __shfl_xor(s.x, 32);
    s.y += __shfl_xor(s.y, 32);
    s.z += __shfl_xor(s.z, 32);
    s.w += __shfl_xor(s.w, 32);
    if (half == 0) {
        float inv = 1.f / fmaxf((float)(p1 - p0), 1.f);
        float4 r = *(const float4*)(tr + (size_t)node * 128 + q4);
        float4 b = *(const float4*)(bl + q4);
        float4 val;
        val.x = fmaf(s.x, inv, b.x) + r.x;
        val.y = fmaf(s.y, inv, b.y) + r.y;
        val.z = fmaf(s.z, inv, b.z) + r.z;
        val.w = fmaf(s.w, inv, b.w) + r.w;
        if (do_bn) {
            float4 g = *(const float4*)(bng + q4);
            float4 be = *(const float4*)(bnb + q4);
            float4 m = *(const float4*)(bnm + q4);
            float4 vv = *(const float4*)(bnv + q4);
            val.x = fmaxf(fmaf(val.x - m.x, g.x * rsqrtf(vv.x + 1e-5f), be.x), 0.f);
            val.y = fmaxf(fmaf(val.y - m.y, g.y * rsqrtf(vv.y + 1e-5f), be.y), 0.f);
            val.z = fmaxf(fmaf(val.z - m.z, g.z * rsqrtf(vv.z + 1e-5f), be.z), 0.f);
            val.w = fmaxf(fmaf(val.w - m.w, g.w * rsqrtf(vv.w + 1e-5f), be.w), 0.f);
        }
        ushort4 hi, lo;
        bsplit(val.x, hi.x, lo.x); bsplit(val.y, hi.y, lo.y);
        bsplit(val.z, hi.z, lo.z); bsplit(val.w, hi.w, lo.w);
        ushort* d = h3 + (size_t)node * 256;
        *(ushort4*)(d + swz(q4, node))       = hi;
        *(ushort4*)(d + swz(q4 + 128, node)) = lo;
    }
}

// ---------------- decoder: relu(u[s] + v[d] + b) . w2 + b2 (u,v fp16) -------
__global__ __launch_bounds__(256) void decode_kernel(
    const ushort* __restrict__ u, const ushort* __restrict__ v,
    const int* __restrict__ eli, const float* __restrict__ db1,
    const float* __restrict__ dw2, const float* __restrict__ db2,
    float* __restrict__ out, int L) {
    __shared__ float sb[128], sw[128];
    if (threadIdx.x < 128) {
        sb[threadIdx.x] = db1[threadIdx.x];
        sw[threadIdx.x] = dw2[threadIdx.x];
    }
    __syncthreads();
    int p = blockIdx.x * 256 + threadIdx.x;
    if (p >= L) return;
    int s = eli[p], d = eli[L + p];
    const ushort* up = u + (size_t)s * 128;
    const ushort* vp = v + (size_t)d * 128;
    float acc = db2[0];
    #pragma unroll 8
    for (int o = 0; o < 128; o += 4) {
        float4 a = h4f(*(const uint2*)(up + o));
        float4 b = h4f(*(const uint2*)(vp + o));
        float4 bb = *(const float4*)(&sb[o]);
        float4 w = *(const float4*)(&sw[o]);
        acc += fmaxf(a.x + b.x + bb.x, 0.f) * w.x;
        acc += fmaxf(a.y + b.y + bb.y, 0.f) * w.y;
        acc += fmaxf(a.z + b.z + bb.z, 0.f) * w.z;
        acc += fmaxf(a.w + b.w + bb.w, 0.f) * w.w;
    }
    out[p] = acc;
}

extern "C" void kernel_launch(void* const* d_in, const int* in_sizes, int n_in,
                              void* d_out, int out_size, void* d_ws, size_t ws_size,
                              hipStream_t stream) {
    const float* x    = (const float*)d_in[0];
    const int*   ei   = (const int*)d_in[1];
    const int*   eli  = (const int*)d_in[2];
    const float* w1l  = (const float*)d_in[3];
    const float* b1l  = (const float*)d_in[4];
    const float* w1r  = (const float*)d_in[5];
    const float* w2l  = (const float*)d_in[6];
    const float* b2l  = (const float*)d_in[7];
    const float* w2r  = (const float*)d_in[8];
    const float* w3l  = (const float*)d_in[9];
    const float* b3l  = (const float*)d_in[10];
    const float* w3r  = (const float*)d_in[11];
    const float* bn1g = (const float*)d_in[12];
    const float* bn1b = (const float*)d_in[13];
    const float* bn1m = (const float*)d_in[14];
    const float* bn1v = (const float*)d_in[15];
    const float* bn2g = (const float*)d_in[16];
    const float* bn2b = (const float*)d_in[17];
    const float* bn2m = (const float*)d_in[18];
    const float* bn2v = (const float*)d_in[19];
    const float* dw1  = (const float*)d_in[20];
    const float* db1  = (const float*)d_in[21];
    const float* dw2  = (const float*)d_in[22];
    const float* db2  = (const float*)d_in[23];
    float* out = (float*)d_out;

    const int N = in_sizes[0] / 256;
    const int E = in_sizes[1] / 2;
    const int L = in_sizes[2] / 2;
    const int* src = ei;
    const int* dst = ei + E;
    const int ntiles = (N + 1023) >> 10;
    const int nblk = (N + 127) / 128;
    const int Npad = nblk * 128;
    const int nconv = (N * 64 + 255) / 256;
    const int ncount = (E + 255) / 256;
    int G16 = (nconv + 11) / 12;
    if ((ncount + 2) / 3 > G16) G16 = (ncount + 2) / 3;
    if (1024 > G16) G16 = 1024;

    char* wsb = (char*)d_ws;
    size_t off = 0;
    auto carve = [&](size_t bytes) -> void* {
        void* p = wsb + off;
        off += (bytes + 255) & ~(size_t)255;
        return p;
    };
    int* ptr        = (int*)carve((size_t)(N + 1) * 4);
    int* cnt        = (int*)carve((size_t)N * 4);
    int* rank       = (int*)carve((size_t)E * 4);
    int* tilesum    = (int*)carve((size_t)ntiles * 4);
    int* edges      = (int*)carve((size_t)E * 4);
    ushort* WS1     = (ushort*)carve((size_t)256 * 768 * 2);
    ushort* WS2     = (ushort*)carve((size_t)256 * 384 * 2);
    ushort* WS3     = (ushort*)carve((size_t)256 * 384 * 2);
    ushort* WS4     = (ushort*)carve((size_t)256 * 384 * 2);
    ushort* tl_h    = (ushort*)carve((size_t)N * 128 * 2);   // neighbor-transform (fp16)
    float* tr_c     = (float*)carve((size_t)N * 128 * 4);    // root-transform (f32) / dec-v (fp16)
    ushort* A3      = (ushort*)carve((size_t)Npad * 512 * 2); // layer-1 [hi|lo]
    ushort* h3      = A3;                                     // reuse: [Npad][256]

    // ---- fused interleaved prologue, then scans + scatter ----
    hipMemsetAsync(cnt, 0, (size_t)N * 4, stream);
    prep_kernel<<<G16 * 16, 256, 0, stream>>>(
        x, A3, N * 64, nconv, dst, cnt, rank, E, ncount,
        w1l, w1r, w2l, w2r, w3l, w3r, dw1, WS1, WS2, WS3, WS4);
    scanA_kernel<<<ntiles, 1024, 0, stream>>>(cnt, ptr, tilesum, N);
    scanC_kernel<<<(N + 255) / 256, 256, 0, stream>>>(ptr, tilesum, N, ntiles);
    scatter_kernel<<<(E + 255) / 256, 256, 0, stream>>>(src, dst, ptr, rank, edges, E);

    // ---- layer 1 ----
    mm_kernel<512, 0><<<nblk, 256, 0, stream>>>(A3, WS1, tl_h, tr_c, N);
    agg_kernel<<<(N + 3) / 4, 256, 0, stream>>>(tl_h, tr_c, ptr, edges, b1l,
                                                bn1g, bn1b, bn1m, bn1v, 1, h3, N);
    // ---- layer 2 ----
    mm_kernel<256, 0><<<nblk, 256, 0, stream>>>(h3, WS2, tl_h, tr_c, N);
    agg_kernel<<<(N + 3) / 4, 256, 0, stream>>>(tl_h, tr_c, ptr, edges, b2l,
                                                bn2g, bn2b, bn2m, bn2v, 1, h3, N);
    // ---- layer 3 (no BN) ----
    mm_kernel<256, 0><<<nblk, 256, 0, stream>>>(h3, WS3, tl_h, tr_c, N);
    agg_kernel<<<(N + 3) / 4, 256, 0, stream>>>(tl_h, tr_c, ptr, edges, b3l,
                                                bn1g, bn1b, bn1m, bn1v, 0, h3, N);
    // ---- decoder transforms u|v (both fp16), then pair decode ----
    mm_kernel<256, 1><<<nblk, 256, 0, stream>>>(h3, WS4, tl_h, tr_c, N);
    decode_kernel<<<(L + 255) / 256, 256, 0, stream>>>(tl_h, (const ushort*)tr_c, eli,
                                                       db1, dw2, db2, out, L);
}

// Round 14
// 313.509 us; speedup vs baseline: 1.3931x; 1.0892x over previous
//
#include <hip/hip_runtime.h>
#include <hip/hip_fp16.h>

// ---------------------------------------------------------------------------
// GraphSAGE (3x SAGEConv mean-agg + BN/ReLU) + link decoder.
// R14 changes vs R13:
//  - GEMM numeric scheme: A = fp16 [hi|lo] split (2^-22 repr), W = SINGLE fp16
//    (2^-11). 2 MFMA terms instead of 3 (bf16 needed 3: both sides 2^-9).
//    Per k-slice: stage {Ah, Al, Wh} (64KB LDS), both halves reuse the same
//    B fragments -> K-steps 12/6/6/6 -> 4/2/2/2, MFMA count x2/3, 4 MFMA per
//    ds_read. Predicted absmax ~1-1.5e-3 (threshold 2.31e-3); revert if over.
//  - everything else identical to R13.
// ---------------------------------------------------------------------------

typedef unsigned int uint;
using f16x8 = __attribute__((ext_vector_type(8))) _Float16;
using f32x4 = __attribute__((ext_vector_type(4))) float;

__device__ inline ushort f2h(float v) { return __half_as_ushort(__float2half(v)); }

// fp16 split: v ~= hi + lo to ~2^-22 rel
__device__ inline void fsplit(float v, ushort& hi, ushort& lo) {
    __half h = __float2half(v);
    hi = __half_as_ushort(h);
    lo = __half_as_ushort(__float2half(v - __half2float(h)));
}

__device__ inline float4 h4f(uint2 r) {
    float2 fa = __half22float2(*(const __half2*)&r.x);
    float2 fb = __half22float2(*(const __half2*)&r.y);
    return make_float4(fa.x, fa.y, fb.x, fb.y);
}

// swizzle a ushort index within its 64-ushort K-slice: chunk ^= (row&7)
__device__ inline uint swz(uint i, uint r) {
    return (i & ~63u) | ((i ^ (r << 3)) & 56u) | (i & 7u);
}

// async global->LDS, 16 bytes per lane
__device__ inline void gload16(const void* g, void* l) {
    __builtin_amdgcn_global_load_lds(
        (const __attribute__((address_space(1))) unsigned int*)g,
        (__attribute__((address_space(3))) unsigned int*)l, 16, 0, 0);
}

// ---------------- fused prologue: interleaved convx | count+rank | wprep ----
__global__ __launch_bounds__(256) void prep_kernel(
    const float* __restrict__ x, ushort* __restrict__ A3, int totalconv, int nconv,
    const int* __restrict__ dst, int* __restrict__ cnt, int* __restrict__ rank,
    int E, int ncount,
    const float* __restrict__ w1l, const float* __restrict__ w1r,
    const float* __restrict__ w2l, const float* __restrict__ w2r,
    const float* __restrict__ w3l, const float* __restrict__ w3r,
    const float* __restrict__ dw1,
    ushort* __restrict__ WS1, ushort* __restrict__ WS2,
    ushort* __restrict__ WS3, ushort* __restrict__ WS4)
{
    const int g = blockIdx.x >> 4;
    const int r16 = blockIdx.x & 15;
    if (r16 < 12) {
        // ---- convx: x[N][256] -> A3[N][512] = fp16 [hi|lo], pre-swizzled
        int ci = g * 12 + r16;
        if (ci >= nconv) return;
        int e = ci * 256 + threadIdx.x;
        if (e >= totalconv) return;
        uint row = e >> 6;
        uint k4 = (e & 63) << 2;
        float4 v = *(const float4*)(x + (size_t)row * 256 + k4);
        ushort4 hi, lo;
        fsplit(v.x, hi.x, lo.x); fsplit(v.y, hi.y, lo.y);
        fsplit(v.z, hi.z, lo.z); fsplit(v.w, hi.w, lo.w);
        ushort* d = A3 + (size_t)row * 512;
        *(ushort4*)(d + swz(k4, row))       = hi;
        *(ushort4*)(d + swz(k4 + 256, row)) = lo;
    } else if (r16 < 15) {
        // ---- count + rank
        int qi = g * 3 + (r16 - 12);
        if (qi >= ncount) return;
        int i = qi * 256 + threadIdx.x;
        if (i < E) rank[i] = atomicAdd(&cnt[dst[i]], 1);
    } else {
        // ---- wprep: 1024 logical blocks = 4 layers x 256 output rows
        int w = g;
        if (w >= 1024) return;
        uint n = w & 255;
        int which = w >> 8;
        uint k = threadIdx.x;
        const float *wa, *wb;
        uint K, lda, aoff, boff;
        ushort* WS;
        switch (which) {
            case 0:  wa = w1l; wb = w1r; K = 256; lda = 256; aoff = 0; boff = 0;   WS = WS1; break;
            case 1:  wa = w2l; wb = w2r; K = 128; lda = 128; aoff = 0; boff = 0;   WS = WS2; break;
            case 2:  wa = w3l; wb = w3r; K = 128; lda = 128; aoff = 0; boff = 0;   WS = WS3; break;
            default: wa = dw1; wb = dw1; K = 128; lda = 256; aoff = 0; boff = 128; WS = WS4; break;
        }
        if (k >= K) return;
        const float* srcr = (n < 128) ? (wa + (size_t)n * lda + aoff)
                                      : (wb + (size_t)(n - 128) * lda + boff);
        ushort* d = WS + (size_t)n * K;            // single fp16 segment
        d[swz(k, n)] = f2h(srcr[k]);
    }
}

// ---------------- scans + scatter ----------------
__global__ void scanA_kernel(const int* __restrict__ cnt, int* __restrict__ ptr,
                             int* __restrict__ tilesum, int n) {
    __shared__ int sd[1024];
    int t = threadIdx.x;
    int i = blockIdx.x * 1024 + t;
    int v = (i < n) ? cnt[i] : 0;
    sd[t] = v;
    __syncthreads();
    #pragma unroll
    for (int off = 1; off < 1024; off <<= 1) {
        int add = (t >= off) ? sd[t - off] : 0;
        __syncthreads();
        sd[t] += add;
        __syncthreads();
    }
    if (i < n) ptr[i] = sd[t] - v;              // local exclusive
    if (t == 1023) tilesum[blockIdx.x] = sd[t]; // tile total
}

// adds tile-prefix (computed locally; <=ntiles uniform loads) + writes ptr[n]
__global__ void scanC_kernel(int* __restrict__ ptr, const int* __restrict__ tilesum,
                             int n, int ntiles) {
    int i = blockIdx.x * 256 + threadIdx.x;
    int t = i >> 10;                            // uniform within a 256-block
    int base = 0;
    for (int b = 0; b < t; ++b) base += tilesum[b];
    if (i < n) ptr[i] += base;
    if (i == 0) {
        int tot = 0;
        for (int b = 0; b < ntiles; ++b) tot += tilesum[b];
        ptr[n] = tot;
    }
}

// atomic-free scatter using precomputed ranks
__global__ void scatter_kernel(const int* __restrict__ src, const int* __restrict__ dst,
                               const int* __restrict__ ptr, const int* __restrict__ rank,
                               int* __restrict__ edges, int E) {
    int i = blockIdx.x * blockDim.x + threadIdx.x;
    if (i < E) edges[ptr[dst[i]] + rank[i]] = src[i];
}

// ---------------- MFMA GEMM (fp16 2-term) ----------------
// Block = 128 rows x 256 cols. 4 waves, each 64x128.
// A[M][2K] = fp16 [hi|lo] pre-swizzled; WS[256][K] fp16 pre-swizzled.
// Per k-slice s: stage Ah_s, Al_s (both 128x64) + Wh_s (256x64) = 64KB LDS;
// both A-halves multiply the SAME B fragments (acc += Ah*W; acc += Al*W).
// Cl (cols 0..127) written fp16; Cr written fp16 iff CRF16 else f32.
template <int K, int CRF16>
__global__ __launch_bounds__(256, 2) void mm_kernel(const ushort* __restrict__ A,
                                                    const ushort* __restrict__ WS,
                                                    ushort* __restrict__ Cl,
                                                    void* __restrict__ Cr_, int M) {
    constexpr int KS = K / 64;                    // 4 (K=256) or 2 (K=128)
    __shared__ ushort At[2 * 128 * 64];           // [hi half | lo half]
    __shared__ ushort Bt[256 * 64];
    const int t = threadIdx.x;
    const int lane = t & 63;
    const int wave = t >> 6;
    const int wm = wave >> 1, wn = wave & 1;      // 2 row-halves x 2 col-halves
    const int row0 = blockIdx.x * 128;
    const int l15 = lane & 15;
    const int l4 = lane >> 4;
    const int l8 = lane >> 3;                     // staging row within 8-row group
    const int c8 = lane & 7;                      // staging chunk within row

    f32x4 acc[4][8] = {};

    for (int s = 0; s < KS; ++s) {
        // ---- stage Ah+Al (2x16KB) and Wh (32KB), linear LDS dest
        #pragma unroll
        for (int j = 0; j < 4; ++j) {
            int jj = wave + j * 4;                // A group 0..15
            int r = jj * 8 + l8;
            const ushort* ga = A + (size_t)(row0 + r) * (2 * K) + s * 64 + c8 * 8;
            gload16(ga,     (char*)At + jj * 1024 + lane * 16);            // hi
            gload16(ga + K, (char*)At + 16384 + jj * 1024 + lane * 16);    // lo
        }
        #pragma unroll
        for (int j = 0; j < 8; ++j) {
            int jj = wave + j * 4;                // B group 0..31
            int r = jj * 8 + l8;
            gload16(WS + (size_t)r * K + s * 64 + c8 * 8,
                    (char*)Bt + jj * 1024 + lane * 16);
        }
        __syncthreads();
        #pragma unroll
        for (int kk = 0; kk < 64; kk += 32) {
            f16x8 bf[8];
            #pragma unroll
            for (int ni = 0; ni < 8; ++ni) {
                int r = wn * 128 + ni * 16 + l15;
                int off = (kk + l4 * 8) ^ ((r & 7) * 8);
                bf[ni] = *(const f16x8*)&Bt[r * 64 + off];
            }
            #pragma unroll
            for (int h = 0; h < 2; ++h) {         // hi then lo, same bf
                f16x8 af[4];
                #pragma unroll
                for (int mi = 0; mi < 4; ++mi) {
                    int r = wm * 64 + mi * 16 + l15;
                    int off = (kk + l4 * 8) ^ ((r & 7) * 8);
                    af[mi] = *(const f16x8*)&At[h * 8192 + r * 64 + off];
                }
                #pragma unroll
                for (int mi = 0; mi < 4; ++mi)
                    #pragma unroll
                    for (int ni = 0; ni < 8; ++ni)
                        acc[mi][ni] = __builtin_amdgcn_mfma_f32_16x16x32_f16(
                            af[mi], bf[ni], acc[mi][ni], 0, 0, 0);
            }
        }
        __syncthreads();
    }
    // ---- epilogue: row = (lane>>4)*4+j, col = lane&15 within 16x16
    #pragma unroll
    for (int mi = 0; mi < 4; ++mi) {
        int rbase = row0 + wm * 64 + mi * 16 + l4 * 4;
        #pragma unroll
        for (int ni = 0; ni < 8; ++ni) {
            int col = ni * 16 + l15;
            #pragma unroll
            for (int j = 0; j < 4; ++j) {
                int r = rbase + j;
                if (r < M) {
                    if (wn == 0) {
                        Cl[(size_t)r * 128 + col] = f2h(acc[mi][ni][j]);
                    } else if (CRF16) {
                        ((ushort*)Cr_)[(size_t)r * 128 + col] = f2h(acc[mi][ni][j]);
                    } else {
                        ((float*)Cr_)[(size_t)r * 128 + col] = acc[mi][ni][j];
                    }
                }
            }
        }
    }
}

// ---------------- aggregation ----------------
// One node per wave; lanes 0-31 even edge slots, 32-63 odd; shfl_xor combine.
// Edge-index prefetch; tl fp16 gathers; root tr f32; emits h[n][256]=[hi|lo].
__global__ __launch_bounds__(256, 4) void agg_kernel(
    const ushort* __restrict__ tl, const float* __restrict__ tr,
    const int* __restrict__ ptr, const int* __restrict__ edges,
    const float* __restrict__ bl,
    const float* __restrict__ bng, const float* __restrict__ bnb,
    const float* __restrict__ bnm, const float* __restrict__ bnv,
    int do_bn, ushort* __restrict__ h3, int n) {
    const int wave = threadIdx.x >> 6;
    const int lane = threadIdx.x & 63;
    const uint node = blockIdx.x * 4 + wave;
    if (node >= (uint)n) return;
    const int half = lane >> 5;
    const uint q4 = (lane & 31) << 2;             // 4 feats per lane
    const int p0 = ptr[node], p1 = ptr[node + 1];
    float4 a0 = make_float4(0.f, 0.f, 0.f, 0.f), a1 = a0, a2 = a0, a3 = a0;
    float4 a4 = a0, a5 = a0, a6 = a0, a7 = a0;
    int e = p0 + half;
    int i0 = 0, i1 = 0, i2 = 0, i3 = 0, i4 = 0, i5 = 0, i6 = 0, i7 = 0;
    bool have = (e + 14 < p1);
    if (have) {
        i0 = edges[e];      i1 = edges[e + 2];  i2 = edges[e + 4];  i3 = edges[e + 6];
        i4 = edges[e + 8];  i5 = edges[e + 10]; i6 = edges[e + 12]; i7 = edges[e + 14];
    }
    while (have) {
        int c0 = i0, c1 = i1, c2 = i2, c3 = i3, c4 = i4, c5 = i5, c6 = i6, c7 = i7;
        e += 16;
        have = (e + 14 < p1);
        if (have) {                               // prefetch next iter's indices
            i0 = edges[e];      i1 = edges[e + 2];  i2 = edges[e + 4];  i3 = edges[e + 6];
            i4 = edges[e + 8];  i5 = edges[e + 10]; i6 = edges[e + 12]; i7 = edges[e + 14];
        }
        uint2 r0 = *(const uint2*)(tl + (size_t)c0 * 128 + q4);
        uint2 r1 = *(const uint2*)(tl + (size_t)c1 * 128 + q4);
        uint2 r2 = *(const uint2*)(tl + (size_t)c2 * 128 + q4);
        uint2 r3 = *(const uint2*)(tl + (size_t)c3 * 128 + q4);
        uint2 r4 = *(const uint2*)(tl + (size_t)c4 * 128 + q4);
        uint2 r5 = *(const uint2*)(tl + (size_t)c5 * 128 + q4);
        uint2 r6 = *(const uint2*)(tl + (size_t)c6 * 128 + q4);
        uint2 r7 = *(const uint2*)(tl + (size_t)c7 * 128 + q4);
        float4 v0 = h4f(r0), v1 = h4f(r1), v2 = h4f(r2), v3 = h4f(r3);
        float4 v4 = h4f(r4), v5 = h4f(r5), v6 = h4f(r6), v7 = h4f(r7);
        a0.x += v0.x; a0.y += v0.y; a0.z += v0.z; a0.w += v0.w;
        a1.x += v1.x; a1.y += v1.y; a1.z += v1.z; a1.w += v1.w;
        a2.x += v2.x; a2.y += v2.y; a2.z += v2.z; a2.w += v2.w;
        a3.x += v3.x; a3.y += v3.y; a3.z += v3.z; a3.w += v3.w;
        a4.x += v4.x; a4.y += v4.y; a4.z += v4.z; a4.w += v4.w;
        a5.x += v5.x; a5.y += v5.y; a5.z += v5.z; a5.w += v5.w;
        a6.x += v6.x; a6.y += v6.y; a6.z += v6.z; a6.w += v6.w;
        a7.x += v7.x; a7.y += v7.y; a7.z += v7.z; a7.w += v7.w;
    }
    // tail: 2 independent gathers per iter
    for (; e + 2 < p1; e += 4) {
        int c0 = edges[e], c1 = edges[e + 2];
        float4 v0 = h4f(*(const uint2*)(tl + (size_t)c0 * 128 + q4));
        float4 v1 = h4f(*(const uint2*)(tl + (size_t)c1 * 128 + q4));
        a0.x += v0.x; a0.y += v0.y; a0.z += v0.z; a0.w += v0.w;
        a1.x += v1.x; a1.y += v1.y; a1.z += v1.z; a1.w += v1.w;
    }
    if (e < p1) {
        int c0 = edges[e];
        float4 v0 = h4f(*(const uint2*)(tl + (size_t)c0 * 128 + q4));
        a2.x += v0.x; a2.y += v0.y; a2.z += v0.z; a2.w += v0.w;
    }
    float4 s;
    s.x = ((a0.x + a1.x) + (a2.x + a3.x)) + ((a4.x + a5.x) + (a6.x + a7.x));
    s.y = ((a0.y + a1.y) + (a2.y + a3.y)) + ((a4.y + a5.y) + (a6.y + a7.y));
    s.z = ((a0.z + a1.z) + (a2.z + a3.z)) + ((a4.z + a5.z) + (a6.z + a7.z));
    s.w = ((a0.w + a1.w) + (a2.w + a3.w)) + ((a4.w + a5.w) + (a6.w + a7.w));
    // combine even/odd halves (lane <-> lane^32)
    s.x += __shfl_xor(s.x, 32);
    s.y += __shfl_xor(s.y, 32);
    s.z += __shfl_xor(s.z, 32);
    s.w += __shfl_xor(s.w, 32);
    if (half == 0) {
        float inv = 1.f / fmaxf((float)(p1 - p0), 1.f);
        float4 r = *(const float4*)(tr + (size_t)node * 128 + q4);
        float4 b = *(const float4*)(bl + q4);
        float4 val;
        val.x = fmaf(s.x, inv, b.x) + r.x;
        val.y = fmaf(s.y, inv, b.y) + r.y;
        val.z = fmaf(s.z, inv, b.z) + r.z;
        val.w = fmaf(s.w, inv, b.w) + r.w;
        if (do_bn) {
            float4 g = *(const float4*)(bng + q4);
            float4 be = *(const float4*)(bnb + q4);
            float4 m = *(const float4*)(bnm + q4);
            float4 vv = *(const float4*)(bnv + q4);
            val.x = fmaxf(fmaf(val.x - m.x, g.x * rsqrtf(vv.x + 1e-5f), be.x), 0.f);
            val.y = fmaxf(fmaf(val.y - m.y, g.y * rsqrtf(vv.y + 1e-5f), be.y), 0.f);
            val.z = fmaxf(fmaf(val.z - m.z, g.z * rsqrtf(vv.z + 1e-5f), be.z), 0.f);
            val.w = fmaxf(fmaf(val.w - m.w, g.w * rsqrtf(vv.w + 1e-5f), be.w), 0.f);
        }
        ushort4 hi, lo;
        fsplit(val.x, hi.x, lo.x); fsplit(val.y, hi.y, lo.y);
        fsplit(val.z, hi.z, lo.z); fsplit(val.w, hi.w, lo.w);
        ushort* d = h3 + (size_t)node * 256;
        *(ushort4*)(d + swz(q4, node))       = hi;
        *(ushort4*)(d + swz(q4 + 128, node)) = lo;
    }
}

// ---------------- decoder: relu(u[s] + v[d] + b) . w2 + b2 (u,v fp16) -------
__global__ __launch_bounds__(256) void decode_kernel(
    const ushort* __restrict__ u, const ushort* __restrict__ v,
    const int* __restrict__ eli, const float* __restrict__ db1,
    const float* __restrict__ dw2, const float* __restrict__ db2,
    float* __restrict__ out, int L) {
    __shared__ float sb[128], sw[128];
    if (threadIdx.x < 128) {
        sb[threadIdx.x] = db1[threadIdx.x];
        sw[threadIdx.x] = dw2[threadIdx.x];
    }
    __syncthreads();
    int p = blockIdx.x * 256 + threadIdx.x;
    if (p >= L) return;
    int s = eli[p], d = eli[L + p];
    const ushort* up = u + (size_t)s * 128;
    const ushort* vp = v + (size_t)d * 128;
    float acc = db2[0];
    #pragma unroll 8
    for (int o = 0; o < 128; o += 4) {
        float4 a = h4f(*(const uint2*)(up + o));
        float4 b = h4f(*(const uint2*)(vp + o));
        float4 bb = *(const float4*)(&sb[o]);
        float4 w = *(const float4*)(&sw[o]);
        acc += fmaxf(a.x + b.x + bb.x, 0.f) * w.x;
        acc += fmaxf(a.y + b.y + bb.y, 0.f) * w.y;
        acc += fmaxf(a.z + b.z + bb.z, 0.f) * w.z;
        acc += fmaxf(a.w + b.w + bb.w, 0.f) * w.w;
    }
    out[p] = acc;
}

extern "C" void kernel_launch(void* const* d_in, const int* in_sizes, int n_in,
                              void* d_out, int out_size, void* d_ws, size_t ws_size,
                              hipStream_t stream) {
    const float* x    = (const float*)d_in[0];
    const int*   ei   = (const int*)d_in[1];
    const int*   eli  = (const int*)d_in[2];
    const float* w1l  = (const float*)d_in[3];
    const float* b1l  = (const float*)d_in[4];
    const float* w1r  = (const float*)d_in[5];
    const float* w2l  = (const float*)d_in[6];
    const float* b2l  = (const float*)d_in[7];
    const float* w2r  = (const float*)d_in[8];
    const float* w3l  = (const float*)d_in[9];
    const float* b3l  = (const float*)d_in[10];
    const float* w3r  = (const float*)d_in[11];
    const float* bn1g = (const float*)d_in[12];
    const float* bn1b = (const float*)d_in[13];
    const float* bn1m = (const float*)d_in[14];
    const float* bn1v = (const float*)d_in[15];
    const float* bn2g = (const float*)d_in[16];
    const float* bn2b = (const float*)d_in[17];
    const float* bn2m = (const float*)d_in[18];
    const float* bn2v = (const float*)d_in[19];
    const float* dw1  = (const float*)d_in[20];
    const float* db1  = (const float*)d_in[21];
    const float* dw2  = (const float*)d_in[22];
    const float* db2  = (const float*)d_in[23];
    float* out = (float*)d_out;

    const int N = in_sizes[0] / 256;
    const int E = in_sizes[1] / 2;
    const int L = in_sizes[2] / 2;
    const int* src = ei;
    const int* dst = ei + E;
    const int ntiles = (N + 1023) >> 10;
    const int nblk = (N + 127) / 128;
    const int Npad = nblk * 128;
    const int nconv = (N * 64 + 255) / 256;
    const int ncount = (E + 255) / 256;
    int G16 = (nconv + 11) / 12;
    if ((ncount + 2) / 3 > G16) G16 = (ncount + 2) / 3;
    if (1024 > G16) G16 = 1024;

    char* wsb = (char*)d_ws;
    size_t off = 0;
    auto carve = [&](size_t bytes) -> void* {
        void* p = wsb + off;
        off += (bytes + 255) & ~(size_t)255;
        return p;
    };
    int* ptr        = (int*)carve((size_t)(N + 1) * 4);
    int* cnt        = (int*)carve((size_t)N * 4);
    int* rank       = (int*)carve((size_t)E * 4);
    int* tilesum    = (int*)carve((size_t)ntiles * 4);
    int* edges      = (int*)carve((size_t)E * 4);
    ushort* WS1     = (ushort*)carve((size_t)256 * 256 * 2);
    ushort* WS2     = (ushort*)carve((size_t)256 * 128 * 2);
    ushort* WS3     = (ushort*)carve((size_t)256 * 128 * 2);
    ushort* WS4     = (ushort*)carve((size_t)256 * 128 * 2);
    ushort* tl_h    = (ushort*)carve((size_t)N * 128 * 2);   // neighbor-transform (fp16)
    float* tr_c     = (float*)carve((size_t)N * 128 * 4);    // root-transform (f32) / dec-v (fp16)
    ushort* A3      = (ushort*)carve((size_t)Npad * 512 * 2); // layer-1 fp16 [hi|lo]
    ushort* h3      = A3;                                     // reuse: [Npad][256]

    // ---- fused interleaved prologue, then scans + scatter ----
    hipMemsetAsync(cnt, 0, (size_t)N * 4, stream);
    prep_kernel<<<G16 * 16, 256, 0, stream>>>(
        x, A3, N * 64, nconv, dst, cnt, rank, E, ncount,
        w1l, w1r, w2l, w2r, w3l, w3r, dw1, WS1, WS2, WS3, WS4);
    scanA_kernel<<<ntiles, 1024, 0, stream>>>(cnt, ptr, tilesum, N);
    scanC_kernel<<<(N + 255) / 256, 256, 0, stream>>>(ptr, tilesum, N, ntiles);
    scatter_kernel<<<(E + 255) / 256, 256, 0, stream>>>(src, dst, ptr, rank, edges, E);

    // ---- layer 1 ----
    mm_kernel<256, 0><<<nblk, 256, 0, stream>>>(A3, WS1, tl_h, tr_c, N);
    agg_kernel<<<(N + 3) / 4, 256, 0, stream>>>(tl_h, tr_c, ptr, edges, b1l,
                                                bn1g, bn1b, bn1m, bn1v, 1, h3, N);
    // ---- layer 2 ----
    mm_kernel<128, 0><<<nblk, 256, 0, stream>>>(h3, WS2, tl_h, tr_c, N);
    agg_kernel<<<(N + 3) / 4, 256, 0, stream>>>(tl_h, tr_c, ptr, edges, b2l,
                                                bn2g, bn2b, bn2m, bn2v, 1, h3, N);
    // ---- layer 3 (no BN) ----
    mm_kernel<128, 0><<<nblk, 256, 0, stream>>>(h3, WS3, tl_h, tr_c, N);
    agg_kernel<<<(N + 3) / 4, 256, 0, stream>>>(tl_h, tr_c, ptr, edges, b3l,
                                                bn1g, bn1b, bn1m, bn1v, 0, h3, N);
    // ---- decoder transforms u|v (both fp16), then pair decode ----
    mm_kernel<128, 1><<<nblk, 256, 0, stream>>>(h3, WS4, tl_h, tr_c, N);
    decode_kernel<<<(L + 255) / 256, 256, 0, stream>>>(tl_h, (const ushort*)tr_c, eli,
                                                       db1, dw2, db2, out, L);
}